// Round 7
// baseline (1144.836 us; speedup 1.0000x reference)
//
#include <hip/hip_runtime.h>
#include <cstdint>
#include <cmath>

typedef __attribute__((ext_vector_type(4))) float floatx4;
typedef __attribute__((ext_vector_type(8))) __bf16 bf16x8;
typedef __attribute__((ext_vector_type(4))) unsigned short ushort4v;

#define DEVI static __device__ __forceinline__

DEVI unsigned short f2b(float f) {
    unsigned x = __float_as_uint(f);
    return (unsigned short)((x + 0x7fffu + ((x >> 16) & 1u)) >> 16);
}
DEVI float b2f(unsigned short u) { return __uint_as_float(((unsigned)u) << 16); }

// async global->LDS, 16B per lane; LDS dest is wave-uniform base + lane*16
DEVI void load16(void* lds, const void* g) {
    __builtin_amdgcn_global_load_lds(
        (__attribute__((address_space(1))) void*)(const_cast<void*>(g)),
        (__attribute__((address_space(3))) void*)lds, 16, 0, 0);
}

DEVI floatx4 MFMA16(bf16x8 a, bf16x8 b, floatx4 c) {
    return __builtin_amdgcn_mfma_f32_16x16x32_bf16(a, b, c, 0, 0, 0);
}

// ---------------------------------------------------------------------------
// fused fp32 -> bf16 weight conversion: 16 segments of 262144 float4 (1MB)
// seg: [0,3)=Wqkv  3=Wout  4..7=Winl{u,a,b,g}  [8,12)=Wff1  [12,16)=Wff2
// ---------------------------------------------------------------------------
__global__ __launch_bounds__(256) void cvt_all(const float* __restrict__ s0,
                                               const float* __restrict__ s1,
                                               const float* __restrict__ s2,
                                               const float* __restrict__ s3,
                                               const float* __restrict__ s4,
                                               const float* __restrict__ s5,
                                               const float* __restrict__ s6,
                                               const float* __restrict__ s7,
                                               unsigned short* d0, unsigned short* d1,
                                               unsigned short* d2, unsigned short* d3,
                                               unsigned short* d4, unsigned short* d5,
                                               unsigned short* d6, unsigned short* d7) {
    int i = blockIdx.x * 256 + threadIdx.x;    // float4 index, 16*262144 total
    int seg = i >> 18;
    int j = i & 262143;
    const float* src; unsigned short* dst;
    if (seg < 3)        { src = s0; dst = d0; j += seg * 262144; }
    else if (seg == 3)  { src = s1; dst = d1; }
    else if (seg == 4)  { src = s2; dst = d2; }
    else if (seg == 5)  { src = s3; dst = d3; }
    else if (seg == 6)  { src = s4; dst = d4; }
    else if (seg == 7)  { src = s5; dst = d5; }
    else if (seg < 12)  { src = s6; dst = d6; j += (seg - 8) * 262144; }
    else                { src = s7; dst = d7; j += (seg - 12) * 262144; }
    floatx4 v = ((const floatx4*)src)[j];
    ushort4v o;
    o[0] = f2b(v[0]); o[1] = f2b(v[1]); o[2] = f2b(v[2]); o[3] = f2b(v[3]);
    ((ushort4v*)dst)[j] = o;
}

__global__ __launch_bounds__(256) void catbias_kernel(const float* __restrict__ a,
                                                      const float* __restrict__ b,
                                                      const float* __restrict__ c,
                                                      const float* __restrict__ d,
                                                      float* __restrict__ o) {
    int i = blockIdx.x * 256 + threadIdx.x;   // 4096 total
    int p = i >> 10, j = i & 1023;
    float v = (p == 0) ? a[j] : (p == 1) ? b[j] : (p == 2) ? c[j] : d[j];
    o[i] = v;
}

// ---------------------------------------------------------------------------
// LayerNorm over D=1024: one block per row, optional bf16 and fp32 outputs
// ---------------------------------------------------------------------------
__global__ __launch_bounds__(256) void ln_kernel(const float* __restrict__ in,
                                                 const float* __restrict__ w,
                                                 const float* __restrict__ b,
                                                 unsigned short* __restrict__ obf,
                                                 float* __restrict__ of) {
    const int row = blockIdx.x, tid = threadIdx.x;
    const floatx4* pr = (const floatx4*)(in + (size_t)row * 1024);
    floatx4 v = pr[tid];
    float s  = v[0] + v[1] + v[2] + v[3];
    float ss = v[0]*v[0] + v[1]*v[1] + v[2]*v[2] + v[3]*v[3];
    #pragma unroll
    for (int o = 32; o >= 1; o >>= 1) { s += __shfl_xor(s, o); ss += __shfl_xor(ss, o); }
    __shared__ float red[8];
    int wv = tid >> 6, lane = tid & 63;
    if (lane == 0) { red[wv] = s; red[4 + wv] = ss; }
    __syncthreads();
    s  = red[0] + red[1] + red[2] + red[3];
    ss = red[4] + red[5] + red[6] + red[7];
    float mu  = s * (1.0f / 1024.0f);
    float var = ss * (1.0f / 1024.0f) - mu * mu;
    float rstd = rsqrtf(var + 1e-5f);
    floatx4 wv4 = ((const floatx4*)w)[tid];
    floatx4 bv4 = ((const floatx4*)b)[tid];
    floatx4 o;
    #pragma unroll
    for (int c = 0; c < 4; c++) o[c] = (v[c] - mu) * rstd * wv4[c] + bv4[c];
    if (obf) {
        ushort4v t;
        t[0] = f2b(o[0]); t[1] = f2b(o[1]); t[2] = f2b(o[2]); t[3] = f2b(o[3]);
        ((ushort4v*)(obf + (size_t)row * 1024))[tid] = t;
    }
    if (of) ((floatx4*)(of + (size_t)row * 1024))[tid] = o;
}

// ---------------------------------------------------------------------------
// INL integrator: 5 explicit steps in registers, then x2 = x1 + xs -> d_out
// ---------------------------------------------------------------------------
__global__ __launch_bounds__(256) void integrator_kernel(const float* __restrict__ xs0,
                                                         const unsigned short* __restrict__ uabg,
                                                         float* __restrict__ xio) {
    size_t i = (size_t)blockIdx.x * 256 + threadIdx.x;  // group of 4 elems
    size_t tok = i >> 8;
    int grp = (int)(i & 255) * 4;
    const unsigned short* ubase = uabg + tok * 4096 + grp;
    ushort4v uu = *(const ushort4v*)(ubase);
    ushort4v aa = *(const ushort4v*)(ubase + 1024);
    ushort4v bb = *(const ushort4v*)(ubase + 2048);
    ushort4v gg = *(const ushort4v*)(ubase + 3072);
    floatx4 xsv = ((const floatx4*)xs0)[i];
    floatx4 x1  = ((const floatx4*)xio)[i];
    floatx4 res;
    #pragma unroll
    for (int c = 0; c < 4; c++) {
        float u = b2f(uu[c]), a = b2f(aa[c]), bt = b2f(bb[c]), g = b2f(gg[c]);
        float xs = xsv[c], vs = 0.f;
        #pragma unroll
        for (int t = 0; t < 5; t++) {
            vs += 0.1f * (-a * xs - bt * vs + u);
            xs += 0.1f * g * vs;
        }
        res[c] = x1[c] + xs;
    }
    ((floatx4*)xio)[i] = res;
}

// ---------------------------------------------------------------------------
// bf16 GEMM v6 (m97-simple + multi-m-tile): each block computes MT=2 stacked
// 128x128 output tiles (256x128 total) sequentially.
//  - amortizes per-block fixed cost (prologue, cold L2/L3 misses) over 2x
//    FLOPs (R5 fit: ~36K cy/block fixed vs ~480 cy/step => T=32 is 50%
//    overhead) and halves B-panel re-reads (each B panel now read by
//    M/256=32 blocks instead of 64 -> FETCH_SIZE should drop).
//  - next m-tile's first K-tile is staged BEFORE the epilogue, so its load
//    latency hides under the epilogue's VALU/stores; the post-epilogue
//    vmcnt(0)+barrier publishes it.  Liveness: buf0's last readers sync at
//    step T-2's trailing barrier (T even), so post-loop stage0 is race-free.
//  - per-tile inner loop identical to R5 (verified).
// EPI: 0=QKV scatter  1=out-proj(+residual,+ctx)  2=INL activations
//      3=FF1 GELU     4=FF2 accumulate into d_out
// ---------------------------------------------------------------------------
template <int EPI>
__global__ __launch_bounds__(256, 4) void gemm_bt(const unsigned short* __restrict__ A,
                                                  const unsigned short* __restrict__ W,
                                                  const float* __restrict__ bias, int K,
                                                  unsigned short* __restrict__ ob0,
                                                  unsigned short* __restrict__ ob1,
                                                  unsigned short* __restrict__ ob2,
                                                  float* __restrict__ of0,
                                                  const float* __restrict__ xres) {
    __shared__ unsigned short sA[2][128 * 32];
    __shared__ unsigned short sB[2][128 * 32];
    const int tid = threadIdx.x;
    const int wave = tid >> 6, lane = tid & 63;
    const int ln = lane & 15, quad = lane >> 4;
    // bijective XCD remap (all launches have nwg % 8 == 0)
    const int gx = gridDim.x;
    const int flat = blockIdx.y * gx + blockIdx.x;
    const int cpx = (gx * (int)gridDim.y) >> 3;
    const int rmp = (flat & 7) * cpx + (flat >> 3);
    const size_t m0s = (size_t)(rmp / gx) * 256;      // 256-row super-tile
    const int n0 = (rmp % gx) * 128;
    const int wm = (wave >> 1) * 64, wn = (wave & 1) * 64;

    const floatx4 z4 = {0.f, 0.f, 0.f, 0.f};
    floatx4 acc[4][4];

    // staging: wave w stages A rows {w*16.., +64}, same for B; source col
    // pre-swizzled, LDS dest linear (verified convention).
    const int r16 = lane >> 2;
    const int gsw = (((lane & 3) ^ (r16 & 3) ^ ((r16 >> 2) & 3))) * 8;
    const int arow = wave * 16 + r16;
    const unsigned short* gA0 = A + (m0s + (size_t)arow) * K + gsw;
    const unsigned short* gA1 = A + (m0s + 128 + (size_t)arow) * K + gsw;
    const unsigned short* gB  = W + ((size_t)(n0 + arow)) * K + gsw;
    const size_t rs64 = (size_t)64 * K;
    const int so = wave * 512;
    const int swr = ((quad ^ (ln & 3) ^ ((ln >> 2) & 3))) * 8;

    const int T = K >> 5;

    auto stage0 = [&](const unsigned short* gA) {   // tile 0 -> buf 0
        load16(&sA[0][so], gA);
        load16(&sA[0][so + 2048], gA + rs64);
        load16(&sB[0][so], gB);
        load16(&sB[0][so + 2048], gB + rs64);
    };

    auto kloop = [&](const unsigned short* gA) {
        #pragma unroll
        for (int mt = 0; mt < 4; mt++)
            #pragma unroll
            for (int nt = 0; nt < 4; nt++) acc[mt][nt] = z4;
        #pragma unroll 1
        for (int t = 0; t < T; t++) {
            const int c = t & 1;
            if (t + 1 < T) {       // stage next tile into the other buffer
                const int k = (t + 1) * 32;
                load16(&sA[c ^ 1][so], gA + k);
                load16(&sA[c ^ 1][so + 2048], gA + rs64 + k);
                load16(&sB[c ^ 1][so], gB + k);
                load16(&sB[c ^ 1][so + 2048], gB + rs64 + k);
            }
            __builtin_amdgcn_sched_barrier(0);
            bf16x8 fa[4], fb[4];
            #pragma unroll
            for (int mt = 0; mt < 4; mt++)
                fa[mt] = *(const bf16x8*)&sA[c][(wm + mt * 16 + ln) * 32 + swr];
            #pragma unroll
            for (int nt = 0; nt < 4; nt++)
                fb[nt] = *(const bf16x8*)&sB[c][(wn + nt * 16 + ln) * 32 + swr];
            asm volatile("s_waitcnt lgkmcnt(0)" ::: "memory");
            __builtin_amdgcn_sched_barrier(0);
            __builtin_amdgcn_s_setprio(1);
            #pragma unroll
            for (int mt = 0; mt < 4; mt++)
                #pragma unroll
                for (int nt = 0; nt < 4; nt++)
                    acc[mt][nt] = MFMA16(fa[mt], fb[nt], acc[mt][nt]);
            __builtin_amdgcn_s_setprio(0);
            __builtin_amdgcn_sched_barrier(0);
            if (t + 1 < T) {
                asm volatile("s_waitcnt vmcnt(0)" ::: "memory");
                asm volatile("s_barrier" ::: "memory");
            }
        }
    };

    auto epilogue = [&](size_t m0b) {
        // C/D layout col=lane&15, row=(lane>>4)*4+reg  [verified m89/m91]
        const size_t rowb = m0b + wm + quad * 4;
        const int colb = n0 + wn + ln;
        #pragma unroll
        for (int mt = 0; mt < 4; mt++) {
            #pragma unroll
            for (int nt = 0; nt < 4; nt++) {
                const int n = colb + nt * 16;
                const float bs = bias[n];
                #pragma unroll
                for (int r = 0; r < 4; r++) {
                    const size_t row = rowb + mt * 16 + r;
                    float c = acc[mt][nt][r] + bs;
                    if constexpr (EPI == 0) {
                        int sect = n >> 10, d1 = n & 1023, h = d1 >> 6, d = d1 & 63;
                        int bb = (int)(row >> 11), s = (int)(row & 2047);
                        size_t bh = (size_t)(bb * 16 + h);
                        if (sect == 0)      ob0[(bh * 2048 + s) * 64 + d] = f2b(c);
                        else if (sect == 1) ob1[(bh * 2048 + s) * 64 + d] = f2b(c);
                        else                ob2[(bh * 64 + d) * 2048 + s] = f2b(c);  // V^T
                    } else if constexpr (EPI == 1) {
                        size_t idx = row * 1024 + n;
                        ob0[idx] = f2b(c);                 // ctx (pre-residual) for INL
                        of0[idx] = xres[idx] + c;          // x1 = x + attn_out
                    } else if constexpr (EPI == 2) {
                        int p = n >> 10;
                        float v;
                        if (p == 0)       v = c;                                            // u
                        else if (p == 2)  v = fmaxf(c, 0.f) + log1pf(__expf(-fabsf(c)));    // softplus
                        else              v = 1.f / (1.f + __expf(-c));                     // sigmoid
                        ob0[row * 4096 + n] = f2b(v);
                    } else if constexpr (EPI == 3) {
                        float v = 0.5f * c * (1.f + erff(c * 0.70710678118654752f));        // exact GELU
                        ob0[row * 4096 + n] = f2b(v);
                    } else {
                        size_t idx = row * 1024 + n;
                        of0[idx] += c;                     // final residual accumulate
                    }
                }
            }
        }
    };

    // ---- m-tile 0 ----
    stage0(gA0);
    asm volatile("s_waitcnt vmcnt(0)" ::: "memory");
    asm volatile("s_barrier" ::: "memory");
    kloop(gA0);
    stage0(gA1);                 // prefetch next m-tile's tile 0 under epilogue
    epilogue(m0s);
    asm volatile("s_waitcnt vmcnt(0)" ::: "memory");
    asm volatile("s_barrier" ::: "memory");
    // ---- m-tile 1 ----
    kloop(gA1);
    epilogue(m0s + 128);
}

// ---------------------------------------------------------------------------
// Flash causal attention (+ setprio around MFMA clusters).
// ---------------------------------------------------------------------------
#define PSTR 72
__global__ __launch_bounds__(256, 3) void attn_kernel(const unsigned short* __restrict__ Qb,
                                                      const unsigned short* __restrict__ Kb,
                                                      const unsigned short* __restrict__ Vtb,
                                                      unsigned short* __restrict__ Ob) {
    __shared__ unsigned short sK[2][64 * 64];
    __shared__ unsigned short sVt[2][64 * 64];
    __shared__ unsigned short sQP[128 * PSTR];
    const int pr = blockIdx.x;
    const int bh = blockIdx.y;
    const int tid = threadIdx.x, wave = tid >> 6, lane = tid & 63;
    const int ln = lane & 15, quad = lane >> 4;
    const unsigned short* Q  = Qb  + (size_t)bh * 2048 * 64;
    const unsigned short* Kp = Kb  + (size_t)bh * 2048 * 64;
    const unsigned short* Vt = Vtb + (size_t)bh * 64 * 2048;

    const int rl  = lane >> 3;
    const int gsw = (((lane & 7) ^ rl)) * 8;
    const int sseg = wave * 2;
    const unsigned short* kbase = Kp + (size_t)(sseg * 8 + rl) * 64 + gsw;
    const unsigned short* vbase = Vt + (size_t)(sseg * 8 + rl) * 2048 + gsw;
    unsigned short* sP = &sQP[wave * 32 * PSTR];
    const int bb = bh >> 4, h = bh & 15;
    const floatx4 z4 = {0.f, 0.f, 0.f, 0.f};

    #pragma unroll 1
    for (int phase = 0; phase < 2; phase++) {
        const int qt = phase ? pr : (15 - pr);
        const int q0 = qt * 128;
        const int T = 2 * qt + 2;

        #pragma unroll
        for (int i = 0; i < 4; i++) {
            int s = wave * 4 + i;
            load16(&sQP[s * 512], Q + (size_t)(q0 + s * 8 + rl) * 64 + gsw);
        }
        load16(&sK[0][sseg * 512], kbase);
        load16(&sK[0][(sseg + 1) * 512], kbase + (size_t)8 * 64);
        load16(&sVt[0][sseg * 512], vbase);
        load16(&sVt[0][(sseg + 1) * 512], vbase + (size_t)8 * 2048);
        asm volatile("s_waitcnt vmcnt(0)" ::: "memory");
        asm volatile("s_barrier" ::: "memory");

        bf16x8 aq[2][2];
        #pragma unroll
        for (int mt = 0; mt < 2; mt++)
            #pragma unroll
            for (int ks = 0; ks < 2; ks++)
                aq[mt][ks] = *(const bf16x8*)&sQP[(wave * 32 + mt * 16 + ln) * 64 +
                                                  (((ks * 4 + quad) ^ (ln & 7)) * 8)];
        asm volatile("s_waitcnt lgkmcnt(0)" ::: "memory");
        asm volatile("s_barrier" ::: "memory");

        floatx4 Oacc[2][4];
        float m_run[2][4], l_run[2][4];
        #pragma unroll
        for (int mt = 0; mt < 2; mt++)
            #pragma unroll
            for (int j = 0; j < 4; j++) { Oacc[mt][j] = z4; m_run[mt][j] = -1e30f; l_run[mt][j] = 0.f; }

        const int wave_first = q0 + wave * 32;
        const int wave_last  = wave_first + 31;

        #pragma unroll 1
        for (int t = 0; t < T; t++) {
            const int kk0 = t * 64;
            const int cur = t & 1;
            if (t + 1 < T) {
                const unsigned short* kg = kbase + (size_t)(kk0 + 64) * 64;
                const unsigned short* vg = vbase + (size_t)(kk0 + 64);
                load16(&sK[cur ^ 1][sseg * 512], kg);
                load16(&sK[cur ^ 1][(sseg + 1) * 512], kg + (size_t)8 * 64);
                load16(&sVt[cur ^ 1][sseg * 512], vg);
                load16(&sVt[cur ^ 1][(sseg + 1) * 512], vg + (size_t)8 * 2048);
                asm volatile("s_waitcnt vmcnt(4)" ::: "memory");
            } else {
                asm volatile("s_waitcnt vmcnt(0)" ::: "memory");
            }
            asm volatile("s_barrier" ::: "memory");

            if (kk0 <= wave_last) {
                floatx4 Sc[2][4];
                #pragma unroll
                for (int mt = 0; mt < 2; mt++)
                    #pragma unroll
                    for (int nt = 0; nt < 4; nt++) Sc[mt][nt] = z4;
                __builtin_amdgcn_s_setprio(1);
                #pragma unroll
                for (int ks = 0; ks < 2; ks++) {
                    #pragma unroll
                    for (int nt = 0; nt < 4; nt++) {
                        bf16x8 bk = *(const bf16x8*)&sK[cur][(nt * 16 + ln) * 64 +
                                                             (((ks * 4 + quad) ^ (ln & 7)) * 8)];
                        #pragma unroll
                        for (int mt = 0; mt < 2; mt++)
                            Sc[mt][nt] = MFMA16(aq[mt][ks], bk, Sc[mt][nt]);
                    }
                }
                __builtin_amdgcn_s_setprio(0);
                const bool diag = (kk0 + 63 > wave_first);
                #pragma unroll
                for (int mt = 0; mt < 2; mt++)
                    #pragma unroll
                    for (int nt = 0; nt < 4; nt++)
                        #pragma unroll
                        for (int r = 0; r < 4; r++) {
                            float v = Sc[mt][nt][r] * 0.125f;
                            if (diag) {
                                int rowg = wave_first + mt * 16 + quad * 4 + r;
                                int colg = kk0 + nt * 16 + ln;
                                if (colg > rowg) v = -1e30f;
                            }
                            Sc[mt][nt][r] = v;
                        }
                float alpha[2][4];
                #pragma unroll
                for (int mt = 0; mt < 2; mt++)
                    #pragma unroll
                    for (int r = 0; r < 4; r++) {
                        float mx = fmaxf(fmaxf(Sc[mt][0][r], Sc[mt][1][r]), fmaxf(Sc[mt][2][r], Sc[mt][3][r]));
                        #pragma unroll
                        for (int off = 1; off < 16; off <<= 1) mx = fmaxf(mx, __shfl_xor(mx, off));
                        float mnew = fmaxf(m_run[mt][r], mx);
                        alpha[mt][r] = __expf(m_run[mt][r] - mnew);
                        m_run[mt][r] = mnew;
                    }
                #pragma unroll
                for (int mt = 0; mt < 2; mt++)
                    #pragma unroll
                    for (int r = 0; r < 4; r++) {
                        float rs = 0.f;
                        #pragma unroll
                        for (int nt = 0; nt < 4; nt++) {
                            float p = __expf(Sc[mt][nt][r] - m_run[mt][r]);
                            Sc[mt][nt][r] = p;
                            rs += p;
                        }
                        #pragma unroll
                        for (int off = 1; off < 16; off <<= 1) rs += __shfl_xor(rs, off);
                        l_run[mt][r] = l_run[mt][r] * alpha[mt][r] + rs;
                    }
                #pragma unroll
                for (int mt = 0; mt < 2; mt++)
                    #pragma unroll
                    for (int nt = 0; nt < 4; nt++)
                        #pragma unroll
                        for (int r = 0; r < 4; r++) Oacc[mt][nt][r] *= alpha[mt][r];
                #pragma unroll
                for (int mt = 0; mt < 2; mt++)
                    #pragma unroll
                    for (int nt = 0; nt < 4; nt++)
                        #pragma unroll
                        for (int r = 0; r < 4; r++)
                            sP[(mt * 16 + quad * 4 + r) * PSTR + nt * 16 + ln] = f2b(Sc[mt][nt][r]);
                __builtin_amdgcn_s_setprio(1);
                #pragma unroll
                for (int kp = 0; kp < 2; kp++) {
                    bf16x8 ap[2];
                    #pragma unroll
                    for (int mt = 0; mt < 2; mt++)
                        ap[mt] = *(const bf16x8*)&sP[(mt * 16 + ln) * PSTR + kp * 32 + quad * 8];
                    #pragma unroll
                    for (int nt = 0; nt < 4; nt++) {
                        bf16x8 bv = *(const bf16x8*)&sVt[cur][(nt * 16 + ln) * 64 +
                                                              (((kp * 4 + quad) ^ (ln & 7)) * 8)];
                        #pragma unroll
                        for (int mt = 0; mt < 2; mt++)
                            Oacc[mt][nt] = MFMA16(ap[mt], bv, Oacc[mt][nt]);
                    }
                }
                __builtin_amdgcn_s_setprio(0);
            }
            asm volatile("s_barrier" ::: "memory");
        }

        #pragma unroll
        for (int mt = 0; mt < 2; mt++)
            #pragma unroll
            for (int nt = 0; nt < 4; nt++)
                #pragma unroll
                for (int r = 0; r < 4; r++) {
                    float o = Oacc[mt][nt][r] / l_run[mt][r];
                    int srow = q0 + wave * 32 + mt * 16 + quad * 4 + r;
                    size_t tok = (size_t)bb * 2048 + srow;
                    Ob[tok * 1024 + h * 64 + nt * 16 + ln] = f2b(o);
                }
    }
}

// ---------------------------------------------------------------------------
extern "C" void kernel_launch(void* const* d_in, const int* in_sizes, int n_in,
                              void* d_out, int out_size, void* d_ws, size_t ws_size,
                              hipStream_t stream) {
    const float* x          = (const float*)d_in[0];
    const float* ln_attn_w  = (const float*)d_in[1];
    const float* ln_attn_b  = (const float*)d_in[2];
    const float* attn_in_w  = (const float*)d_in[3];
    const float* attn_in_b  = (const float*)d_in[4];
    const float* attn_out_w = (const float*)d_in[5];
    const float* attn_out_b = (const float*)d_in[6];
    const float* ln1_w      = (const float*)d_in[7];
    const float* ln1_b      = (const float*)d_in[8];
    const float* ln2_w      = (const float*)d_in[9];
    const float* ln2_b      = (const float*)d_in[10];
    const float* inl_u_w    = (const float*)d_in[11];
    const float* inl_u_b    = (const float*)d_in[12];
    const float* inl_a_w    = (const float*)d_in[13];
    const float* inl_a_b    = (const float*)d_in[14];
    const float* inl_b_w    = (const float*)d_in[15];
    const float* inl_b_b    = (const float*)d_in[16];
    const float* inl_g_w    = (const float*)d_in[17];
    const float* inl_g_b    = (const float*)d_in[18];
    const float* ff1_w      = (const float*)d_in[19];
    const float* ff1_b      = (const float*)d_in[20];
    const float* ff2_w      = (const float*)d_in[21];
    const float* ff2_b      = (const float*)d_in[22];
    float* out = (float*)d_out;

    char* ws = (char*)d_ws;
    unsigned short* Wqkv  = (unsigned short*)(ws);
    unsigned short* Wout  = (unsigned short*)(ws + 6291456);
    unsigned short* Winl  = (unsigned short*)(ws + 8388608);
    unsigned short* Wff1  = (unsigned short*)(ws + 16777216);
    unsigned short* Wff2  = (unsigned short*)(ws + 25165824);
    unsigned short* xnb   = (unsigned short*)(ws + 33554432);   // 16MB: xn, later h
    unsigned short* qb    = (unsigned short*)(ws + 50331648);   // 16MB
    unsigned short* kb    = (unsigned short*)(ws + 67108864);   // 16MB
    unsigned short* vtb   = (unsigned short*)(ws + 83886080);   // 16MB
    unsigned short* attnb = (unsigned short*)(ws + 100663296);  // 16MB
    unsigned short* ctxb  = (unsigned short*)(ws + 117440512);  // 16MB
    float*          xs    = (float*)(ws + 134217728);           // 32MB
    float*          bias4 = (float*)(ws + 167772160);           // 16KB
    unsigned short* uabg  = (unsigned short*)(ws + 50331648);   // 64MB, reuses q/k/vt/attn
    unsigned short* ff1b  = (unsigned short*)(ws + 50331648);   // 64MB, reuses uabg

    // 1. fused weight conversion (one launch) + bias concat
    cvt_all<<<16384, 256, 0, stream>>>(attn_in_w, attn_out_w, inl_u_w, inl_a_w,
                                       inl_b_w, inl_g_w, ff1_w, ff2_w,
                                       Wqkv, Wout, Winl, Winl + 1048576,
                                       Winl + 2097152, Winl + 3145728, Wff1, Wff2);
    catbias_kernel<<<16, 256, 0, stream>>>(inl_u_b, inl_a_b, inl_b_b, inl_g_b, bias4);

    // 2. xn = LN(x)
    ln_kernel<<<8192, 256, 0, stream>>>(x, ln_attn_w, ln_attn_b, xnb, nullptr);
    // 3. qkv projection (MT=2), scattered into per-head q/k/v^T
    gemm_bt<0><<<dim3(24, 32), 256, 0, stream>>>(xnb, Wqkv, attn_in_b, 1024, qb, kb, vtb, nullptr, nullptr);
    // 4. causal flash attention (balanced pairs)
    attn_kernel<<<dim3(8, 64), 256, 0, stream>>>(qb, kb, vtb, attnb);
    // 5. out-projection: ctx (bf16) + x1 = x + ctx -> d_out
    gemm_bt<1><<<dim3(8, 32), 256, 0, stream>>>(attnb, Wout, attn_out_b, 1024, ctxb, nullptr, nullptr, out, x);
    // 6. xs0 = LN(x1)
    ln_kernel<<<8192, 256, 0, stream>>>(out, ln1_w, ln1_b, nullptr, xs);
    // 7. fused INL controllers: u | sigmoid | softplus | sigmoid
    gemm_bt<2><<<dim3(32, 32), 256, 0, stream>>>(ctxb, Winl, bias4, 1024, uabg, nullptr, nullptr, nullptr, nullptr);
    // 8. integrator: x2 = x1 + xs(5 steps) -> d_out
    integrator_kernel<<<8192, 256, 0, stream>>>(xs, uabg, out);
    // 9. h = LN(x2)
    ln_kernel<<<8192, 256, 0, stream>>>(out, ln2_w, ln2_b, xnb, nullptr);
    // 10. FF1 + exact GELU (MT=2)
    gemm_bt<3><<<dim3(32, 32), 256, 0, stream>>>(xnb, Wff1, ff1_b, 1024, ff1b, nullptr, nullptr, nullptr, nullptr);
    // 11. FF2 + residual accumulate -> d_out (MT=2)
    gemm_bt<4><<<dim3(8, 32), 256, 0, stream>>>(ff1b, Wff2, ff2_b, 4096, nullptr, nullptr, nullptr, out, nullptr);
}

// Round 8
// 860.232 us; speedup vs baseline: 1.3308x; 1.3308x over previous
//
#include <hip/hip_runtime.h>
#include <cstdint>
#include <cmath>

typedef __attribute__((ext_vector_type(4))) float floatx4;
typedef __attribute__((ext_vector_type(8))) __bf16 bf16x8;
typedef __attribute__((ext_vector_type(4))) unsigned short ushort4v;

#define DEVI static __device__ __forceinline__

DEVI unsigned short f2b(float f) {
    unsigned x = __float_as_uint(f);
    return (unsigned short)((x + 0x7fffu + ((x >> 16) & 1u)) >> 16);
}
DEVI float b2f(unsigned short u) { return __uint_as_float(((unsigned)u) << 16); }

// async global->LDS, 16B per lane; LDS dest is wave-uniform base + lane*16
DEVI void load16(void* lds, const void* g) {
    __builtin_amdgcn_global_load_lds(
        (__attribute__((address_space(1))) void*)(const_cast<void*>(g)),
        (__attribute__((address_space(3))) void*)lds, 16, 0, 0);
}

DEVI floatx4 MFMA16(bf16x8 a, bf16x8 b, floatx4 c) {
    return __builtin_amdgcn_mfma_f32_16x16x32_bf16(a, b, c, 0, 0, 0);
}

// ---------------------------------------------------------------------------
// fused fp32 -> bf16 weight conversion: 16 segments of 262144 float4 (1MB)
// seg: [0,3)=Wqkv  3=Wout  4..7=Winl{u,a,b,g}  [8,12)=Wff1  [12,16)=Wff2
// ---------------------------------------------------------------------------
__global__ __launch_bounds__(256) void cvt_all(const float* __restrict__ s0,
                                               const float* __restrict__ s1,
                                               const float* __restrict__ s2,
                                               const float* __restrict__ s3,
                                               const float* __restrict__ s4,
                                               const float* __restrict__ s5,
                                               const float* __restrict__ s6,
                                               const float* __restrict__ s7,
                                               unsigned short* d0, unsigned short* d1,
                                               unsigned short* d2, unsigned short* d3,
                                               unsigned short* d4, unsigned short* d5,
                                               unsigned short* d6, unsigned short* d7) {
    int i = blockIdx.x * 256 + threadIdx.x;    // float4 index, 16*262144 total
    int seg = i >> 18;
    int j = i & 262143;
    const float* src; unsigned short* dst;
    if (seg < 3)        { src = s0; dst = d0; j += seg * 262144; }
    else if (seg == 3)  { src = s1; dst = d1; }
    else if (seg == 4)  { src = s2; dst = d2; }
    else if (seg == 5)  { src = s3; dst = d3; }
    else if (seg == 6)  { src = s4; dst = d4; }
    else if (seg == 7)  { src = s5; dst = d5; }
    else if (seg < 12)  { src = s6; dst = d6; j += (seg - 8) * 262144; }
    else                { src = s7; dst = d7; j += (seg - 12) * 262144; }
    floatx4 v = ((const floatx4*)src)[j];
    ushort4v o;
    o[0] = f2b(v[0]); o[1] = f2b(v[1]); o[2] = f2b(v[2]); o[3] = f2b(v[3]);
    ((ushort4v*)dst)[j] = o;
}

__global__ __launch_bounds__(256) void catbias_kernel(const float* __restrict__ a,
                                                      const float* __restrict__ b,
                                                      const float* __restrict__ c,
                                                      const float* __restrict__ d,
                                                      float* __restrict__ o) {
    int i = blockIdx.x * 256 + threadIdx.x;   // 4096 total
    int p = i >> 10, j = i & 1023;
    float v = (p == 0) ? a[j] : (p == 1) ? b[j] : (p == 2) ? c[j] : d[j];
    o[i] = v;
}

// ---------------------------------------------------------------------------
// LayerNorm over D=1024: one block per row, bf16 output (used for LN(x) only)
// ---------------------------------------------------------------------------
__global__ __launch_bounds__(256) void ln_kernel(const float* __restrict__ in,
                                                 const float* __restrict__ w,
                                                 const float* __restrict__ b,
                                                 unsigned short* __restrict__ obf) {
    const int row = blockIdx.x, tid = threadIdx.x;
    const floatx4* pr = (const floatx4*)(in + (size_t)row * 1024);
    floatx4 v = pr[tid];
    float s  = v[0] + v[1] + v[2] + v[3];
    float ss = v[0]*v[0] + v[1]*v[1] + v[2]*v[2] + v[3]*v[3];
    #pragma unroll
    for (int o = 32; o >= 1; o >>= 1) { s += __shfl_xor(s, o); ss += __shfl_xor(ss, o); }
    __shared__ float red[8];
    int wv = tid >> 6, lane = tid & 63;
    if (lane == 0) { red[wv] = s; red[4 + wv] = ss; }
    __syncthreads();
    s  = red[0] + red[1] + red[2] + red[3];
    ss = red[4] + red[5] + red[6] + red[7];
    float mu  = s * (1.0f / 1024.0f);
    float var = ss * (1.0f / 1024.0f) - mu * mu;
    float rstd = rsqrtf(var + 1e-5f);
    floatx4 wv4 = ((const floatx4*)w)[tid];
    floatx4 bv4 = ((const floatx4*)b)[tid];
    ushort4v t;
    #pragma unroll
    for (int c = 0; c < 4; c++) t[c] = f2b((v[c] - mu) * rstd * wv4[c] + bv4[c]);
    ((ushort4v*)(obf + (size_t)row * 1024))[tid] = t;
}

// ---------------------------------------------------------------------------
// FUSED ln1 + INL integrator + ln2 (one block = one token, 256 thr x 4 elems):
//   x1 = xio[row]           (fp32, read once)
//   xs = LN(x1; w1,b1)      (in-register, block reduction)
//   5 integration steps with uabg -> x2 = x1 + xs
//   xio[row] = x2           (fp32)
//   h  = LN(x2; w2,b2) -> hb (bf16, feeds FF1)
// Replaces ln1 + integrator + ln2: saves xs buffer (32MB w + 32MB r),
// x1 re-read (32MB), x2 re-read (32MB) and 2 launches.
// ---------------------------------------------------------------------------
__global__ __launch_bounds__(256) void integrator_ln_kernel(const float* __restrict__ w1,
                                                            const float* __restrict__ b1,
                                                            const float* __restrict__ w2,
                                                            const float* __restrict__ b2,
                                                            const unsigned short* __restrict__ uabg,
                                                            float* __restrict__ xio,
                                                            unsigned short* __restrict__ hb) {
    const int row = blockIdx.x, tid = threadIdx.x;
    const int wv = tid >> 6, lane = tid & 63;
    __shared__ float red[8], red2[8];

    // ---- load x1, LN1 reduction ----
    floatx4 v = ((const floatx4*)(xio + (size_t)row * 1024))[tid];
    float s  = v[0] + v[1] + v[2] + v[3];
    float ss = v[0]*v[0] + v[1]*v[1] + v[2]*v[2] + v[3]*v[3];
    #pragma unroll
    for (int o = 32; o >= 1; o >>= 1) { s += __shfl_xor(s, o); ss += __shfl_xor(ss, o); }
    if (lane == 0) { red[wv] = s; red[4 + wv] = ss; }
    __syncthreads();
    s  = red[0] + red[1] + red[2] + red[3];
    ss = red[4] + red[5] + red[6] + red[7];
    float mu  = s * (1.0f / 1024.0f);
    float rstd = rsqrtf(ss * (1.0f / 1024.0f) - mu * mu + 1e-5f);
    floatx4 w1v = ((const floatx4*)w1)[tid];
    floatx4 b1v = ((const floatx4*)b1)[tid];

    // ---- integrator (5 steps, registers) ----
    const unsigned short* ubase = uabg + (size_t)row * 4096 + tid * 4;
    ushort4v uu = *(const ushort4v*)(ubase);
    ushort4v aa = *(const ushort4v*)(ubase + 1024);
    ushort4v bb = *(const ushort4v*)(ubase + 2048);
    ushort4v gg = *(const ushort4v*)(ubase + 3072);
    floatx4 res;
    #pragma unroll
    for (int c = 0; c < 4; c++) {
        float xs = (v[c] - mu) * rstd * w1v[c] + b1v[c];
        float u = b2f(uu[c]), a = b2f(aa[c]), bt = b2f(bb[c]), g = b2f(gg[c]);
        float vs = 0.f;
        #pragma unroll
        for (int t = 0; t < 5; t++) {
            vs += 0.1f * (-a * xs - bt * vs + u);
            xs += 0.1f * g * vs;
        }
        res[c] = v[c] + xs;
    }
    ((floatx4*)(xio + (size_t)row * 1024))[tid] = res;   // x2

    // ---- LN2 on x2 ----
    float s2  = res[0] + res[1] + res[2] + res[3];
    float ss2 = res[0]*res[0] + res[1]*res[1] + res[2]*res[2] + res[3]*res[3];
    #pragma unroll
    for (int o = 32; o >= 1; o >>= 1) { s2 += __shfl_xor(s2, o); ss2 += __shfl_xor(ss2, o); }
    if (lane == 0) { red2[wv] = s2; red2[4 + wv] = ss2; }
    __syncthreads();
    s2  = red2[0] + red2[1] + red2[2] + red2[3];
    ss2 = red2[4] + red2[5] + red2[6] + red2[7];
    float mu2  = s2 * (1.0f / 1024.0f);
    float rstd2 = rsqrtf(ss2 * (1.0f / 1024.0f) - mu2 * mu2 + 1e-5f);
    floatx4 w2v = ((const floatx4*)w2)[tid];
    floatx4 b2v = ((const floatx4*)b2)[tid];
    ushort4v t;
    #pragma unroll
    for (int c = 0; c < 4; c++) t[c] = f2b((res[c] - mu2) * rstd2 * w2v[c] + b2v[c]);
    ((ushort4v*)(hb + (size_t)row * 1024))[tid] = t;
}

// ---------------------------------------------------------------------------
// bf16 GEMM (R1 config — best measured): C[M,N] = A[M,K] @ W[N,K]^T (+bias).
// 128x128 tile, BK=32, 4 waves, TRIPLE-buffered LDS + reg-dbuf frags,
// counted vmcnt(4), loads->MFMA->wait->ds_read reorder, setprio.
// EPI: 0=QKV scatter  1=out-proj(+residual,+ctx)  2=INL activations
//      3=FF1 GELU     4=FF2 accumulate into d_out
// ---------------------------------------------------------------------------
template <int EPI>
__global__ __launch_bounds__(256, 3) void gemm_bt(const unsigned short* __restrict__ A,
                                                  const unsigned short* __restrict__ W,
                                                  const float* __restrict__ bias, int K,
                                                  unsigned short* __restrict__ ob0,
                                                  unsigned short* __restrict__ ob1,
                                                  unsigned short* __restrict__ ob2,
                                                  float* __restrict__ of0,
                                                  const float* __restrict__ xres) {
    __shared__ unsigned short sA[3][128 * 32];
    __shared__ unsigned short sB[3][128 * 32];
    const int tid = threadIdx.x;
    const int wave = tid >> 6, lane = tid & 63;
    const int ln = lane & 15, quad = lane >> 4;
    const size_t m0 = (size_t)blockIdx.y * 128;
    const int n0 = blockIdx.x * 128;
    const int wm = (wave >> 1) * 64, wn = (wave & 1) * 64;

    const floatx4 z4 = {0.f, 0.f, 0.f, 0.f};
    floatx4 acc[4][4];
    #pragma unroll
    for (int mt = 0; mt < 4; mt++)
        #pragma unroll
        for (int nt = 0; nt < 4; nt++) acc[mt][nt] = z4;

    const int r16 = lane >> 2;
    const int gsw = (((lane & 3) ^ (r16 & 3) ^ ((r16 >> 2) & 3))) * 8;
    const int arow = wave * 16 + r16;
    const unsigned short* gA = A + (m0 + (size_t)arow) * K + gsw;
    const unsigned short* gB = W + ((size_t)(n0 + arow)) * K + gsw;
    const size_t rs64 = (size_t)64 * K;
    const int so = wave * 512;
    const int swr = ((quad ^ (ln & 3) ^ ((ln >> 2) & 3))) * 8;

    const int T = K >> 5;

    // prologue: tile 0 -> buf 0, tile 1 -> buf 1
    load16(&sA[0][so], gA);
    load16(&sA[0][so + 2048], gA + rs64);
    load16(&sB[0][so], gB);
    load16(&sB[0][so + 2048], gB + rs64);
    load16(&sA[1][so], gA + 32);
    load16(&sA[1][so + 2048], gA + rs64 + 32);
    load16(&sB[1][so], gB + 32);
    load16(&sB[1][so + 2048], gB + rs64 + 32);
    asm volatile("s_waitcnt vmcnt(4)" ::: "memory");
    asm volatile("s_barrier" ::: "memory");

    bf16x8 fa0[4], fb0[4], fa1[4], fb1[4];
    #pragma unroll
    for (int mt = 0; mt < 4; mt++)
        fa0[mt] = *(const bf16x8*)&sA[0][(wm + mt * 16 + ln) * 32 + swr];
    #pragma unroll
    for (int nt = 0; nt < 4; nt++)
        fb0[nt] = *(const bf16x8*)&sB[0][(wn + nt * 16 + ln) * 32 + swr];

    auto step = [&](int t, bf16x8* afc, bf16x8* bfc, bf16x8* afn, bf16x8* bfn) {
        if (t + 2 < T) {
            const int k = (t + 2) * 32;
            const int nb = (t + 2) % 3;
            load16(&sA[nb][so], gA + k);
            load16(&sA[nb][so + 2048], gA + rs64 + k);
            load16(&sB[nb][so], gB + k);
            load16(&sB[nb][so + 2048], gB + rs64 + k);
        }
        __builtin_amdgcn_sched_barrier(0);
        __builtin_amdgcn_s_setprio(1);
        #pragma unroll
        for (int mt = 0; mt < 4; mt++)
            #pragma unroll
            for (int nt = 0; nt < 4; nt++)
                acc[mt][nt] = MFMA16(afc[mt], bfc[nt], acc[mt][nt]);
        __builtin_amdgcn_s_setprio(0);
        __builtin_amdgcn_sched_barrier(0);
        if (t + 1 < T) {
            if (t + 2 < T) {
                asm volatile("s_waitcnt vmcnt(4) lgkmcnt(0)" ::: "memory");
            } else {
                asm volatile("s_waitcnt vmcnt(0) lgkmcnt(0)" ::: "memory");
            }
            asm volatile("s_barrier" ::: "memory");
            const int nb = (t + 1) % 3;
            afn[0] = *(const bf16x8*)&sA[nb][(wm + ln) * 32 + swr];
            #pragma unroll
            for (int nt = 0; nt < 4; nt++)
                bfn[nt] = *(const bf16x8*)&sB[nb][(wn + nt * 16 + ln) * 32 + swr];
            #pragma unroll
            for (int mt = 1; mt < 4; mt++)
                afn[mt] = *(const bf16x8*)&sA[nb][(wm + mt * 16 + ln) * 32 + swr];
        }
    };

    #pragma unroll 1
    for (int t = 0; t < T; t += 2) {
        step(t, fa0, fb0, fa1, fb1);
        step(t + 1, fa1, fb1, fa0, fb0);
    }

    // epilogue: C/D layout col=lane&15, row=(lane>>4)*4+reg  [verified m89/m91]
    const size_t rowb = m0 + wm + quad * 4;
    const int colb = n0 + wn + ln;
    #pragma unroll
    for (int mt = 0; mt < 4; mt++) {
        #pragma unroll
        for (int nt = 0; nt < 4; nt++) {
            const int n = colb + nt * 16;
            const float bs = bias[n];
            #pragma unroll
            for (int r = 0; r < 4; r++) {
                const size_t row = rowb + mt * 16 + r;
                float c = acc[mt][nt][r] + bs;
                if constexpr (EPI == 0) {
                    int sect = n >> 10, d1 = n & 1023, h = d1 >> 6, d = d1 & 63;
                    int bb = (int)(row >> 11), s = (int)(row & 2047);
                    size_t bh = (size_t)(bb * 16 + h);
                    if (sect == 0)      ob0[(bh * 2048 + s) * 64 + d] = f2b(c);
                    else if (sect == 1) ob1[(bh * 2048 + s) * 64 + d] = f2b(c);
                    else                ob2[(bh * 64 + d) * 2048 + s] = f2b(c);  // V^T
                } else if constexpr (EPI == 1) {
                    size_t idx = row * 1024 + n;
                    ob0[idx] = f2b(c);                 // ctx (pre-residual) for INL
                    of0[idx] = xres[idx] + c;          // x1 = x + attn_out
                } else if constexpr (EPI == 2) {
                    int p = n >> 10;
                    float v;
                    if (p == 0)       v = c;                                            // u
                    else if (p == 2)  v = fmaxf(c, 0.f) + log1pf(__expf(-fabsf(c)));    // softplus
                    else              v = 1.f / (1.f + __expf(-c));                     // sigmoid
                    ob0[row * 4096 + n] = f2b(v);
                } else if constexpr (EPI == 3) {
                    float v = 0.5f * c * (1.f + erff(c * 0.70710678118654752f));        // exact GELU
                    ob0[row * 4096 + n] = f2b(v);
                } else {
                    size_t idx = row * 1024 + n;
                    of0[idx] += c;                     // final residual accumulate
                }
            }
        }
    }
}

// ---------------------------------------------------------------------------
// Flash causal attention (+ setprio around MFMA clusters).
// ---------------------------------------------------------------------------
#define PSTR 72
__global__ __launch_bounds__(256, 3) void attn_kernel(const unsigned short* __restrict__ Qb,
                                                      const unsigned short* __restrict__ Kb,
                                                      const unsigned short* __restrict__ Vtb,
                                                      unsigned short* __restrict__ Ob) {
    __shared__ unsigned short sK[2][64 * 64];
    __shared__ unsigned short sVt[2][64 * 64];
    __shared__ unsigned short sQP[128 * PSTR];
    const int pr = blockIdx.x;
    const int bh = blockIdx.y;
    const int tid = threadIdx.x, wave = tid >> 6, lane = tid & 63;
    const int ln = lane & 15, quad = lane >> 4;
    const unsigned short* Q  = Qb  + (size_t)bh * 2048 * 64;
    const unsigned short* Kp = Kb  + (size_t)bh * 2048 * 64;
    const unsigned short* Vt = Vtb + (size_t)bh * 64 * 2048;

    const int rl  = lane >> 3;
    const int gsw = (((lane & 7) ^ rl)) * 8;
    const int sseg = wave * 2;
    const unsigned short* kbase = Kp + (size_t)(sseg * 8 + rl) * 64 + gsw;
    const unsigned short* vbase = Vt + (size_t)(sseg * 8 + rl) * 2048 + gsw;
    unsigned short* sP = &sQP[wave * 32 * PSTR];
    const int bb = bh >> 4, h = bh & 15;
    const floatx4 z4 = {0.f, 0.f, 0.f, 0.f};

    #pragma unroll 1
    for (int phase = 0; phase < 2; phase++) {
        const int qt = phase ? pr : (15 - pr);
        const int q0 = qt * 128;
        const int T = 2 * qt + 2;

        #pragma unroll
        for (int i = 0; i < 4; i++) {
            int s = wave * 4 + i;
            load16(&sQP[s * 512], Q + (size_t)(q0 + s * 8 + rl) * 64 + gsw);
        }
        load16(&sK[0][sseg * 512], kbase);
        load16(&sK[0][(sseg + 1) * 512], kbase + (size_t)8 * 64);
        load16(&sVt[0][sseg * 512], vbase);
        load16(&sVt[0][(sseg + 1) * 512], vbase + (size_t)8 * 2048);
        asm volatile("s_waitcnt vmcnt(0)" ::: "memory");
        asm volatile("s_barrier" ::: "memory");

        bf16x8 aq[2][2];
        #pragma unroll
        for (int mt = 0; mt < 2; mt++)
            #pragma unroll
            for (int ks = 0; ks < 2; ks++)
                aq[mt][ks] = *(const bf16x8*)&sQP[(wave * 32 + mt * 16 + ln) * 64 +
                                                  (((ks * 4 + quad) ^ (ln & 7)) * 8)];
        asm volatile("s_waitcnt lgkmcnt(0)" ::: "memory");
        asm volatile("s_barrier" ::: "memory");

        floatx4 Oacc[2][4];
        float m_run[2][4], l_run[2][4];
        #pragma unroll
        for (int mt = 0; mt < 2; mt++)
            #pragma unroll
            for (int j = 0; j < 4; j++) { Oacc[mt][j] = z4; m_run[mt][j] = -1e30f; l_run[mt][j] = 0.f; }

        const int wave_first = q0 + wave * 32;
        const int wave_last  = wave_first + 31;

        #pragma unroll 1
        for (int t = 0; t < T; t++) {
            const int kk0 = t * 64;
            const int cur = t & 1;
            if (t + 1 < T) {
                const unsigned short* kg = kbase + (size_t)(kk0 + 64) * 64;
                const unsigned short* vg = vbase + (size_t)(kk0 + 64);
                load16(&sK[cur ^ 1][sseg * 512], kg);
                load16(&sK[cur ^ 1][(sseg + 1) * 512], kg + (size_t)8 * 64);
                load16(&sVt[cur ^ 1][sseg * 512], vg);
                load16(&sVt[cur ^ 1][(sseg + 1) * 512], vg + (size_t)8 * 2048);
                asm volatile("s_waitcnt vmcnt(4)" ::: "memory");
            } else {
                asm volatile("s_waitcnt vmcnt(0)" ::: "memory");
            }
            asm volatile("s_barrier" ::: "memory");

            if (kk0 <= wave_last) {
                floatx4 Sc[2][4];
                #pragma unroll
                for (int mt = 0; mt < 2; mt++)
                    #pragma unroll
                    for (int nt = 0; nt < 4; nt++) Sc[mt][nt] = z4;
                __builtin_amdgcn_s_setprio(1);
                #pragma unroll
                for (int ks = 0; ks < 2; ks++) {
                    #pragma unroll
                    for (int nt = 0; nt < 4; nt++) {
                        bf16x8 bk = *(const bf16x8*)&sK[cur][(nt * 16 + ln) * 64 +
                                                             (((ks * 4 + quad) ^ (ln & 7)) * 8)];
                        #pragma unroll
                        for (int mt = 0; mt < 2; mt++)
                            Sc[mt][nt] = MFMA16(aq[mt][ks], bk, Sc[mt][nt]);
                    }
                }
                __builtin_amdgcn_s_setprio(0);
                const bool diag = (kk0 + 63 > wave_first);
                #pragma unroll
                for (int mt = 0; mt < 2; mt++)
                    #pragma unroll
                    for (int nt = 0; nt < 4; nt++)
                        #pragma unroll
                        for (int r = 0; r < 4; r++) {
                            float v = Sc[mt][nt][r] * 0.125f;
                            if (diag) {
                                int rowg = wave_first + mt * 16 + quad * 4 + r;
                                int colg = kk0 + nt * 16 + ln;
                                if (colg > rowg) v = -1e30f;
                            }
                            Sc[mt][nt][r] = v;
                        }
                float alpha[2][4];
                #pragma unroll
                for (int mt = 0; mt < 2; mt++)
                    #pragma unroll
                    for (int r = 0; r < 4; r++) {
                        float mx = fmaxf(fmaxf(Sc[mt][0][r], Sc[mt][1][r]), fmaxf(Sc[mt][2][r], Sc[mt][3][r]));
                        #pragma unroll
                        for (int off = 1; off < 16; off <<= 1) mx = fmaxf(mx, __shfl_xor(mx, off));
                        float mnew = fmaxf(m_run[mt][r], mx);
                        alpha[mt][r] = __expf(m_run[mt][r] - mnew);
                        m_run[mt][r] = mnew;
                    }
                #pragma unroll
                for (int mt = 0; mt < 2; mt++)
                    #pragma unroll
                    for (int r = 0; r < 4; r++) {
                        float rs = 0.f;
                        #pragma unroll
                        for (int nt = 0; nt < 4; nt++) {
                            float p = __expf(Sc[mt][nt][r] - m_run[mt][r]);
                            Sc[mt][nt][r] = p;
                            rs += p;
                        }
                        #pragma unroll
                        for (int off = 1; off < 16; off <<= 1) rs += __shfl_xor(rs, off);
                        l_run[mt][r] = l_run[mt][r] * alpha[mt][r] + rs;
                    }
                #pragma unroll
                for (int mt = 0; mt < 2; mt++)
                    #pragma unroll
                    for (int nt = 0; nt < 4; nt++)
                        #pragma unroll
                        for (int r = 0; r < 4; r++) Oacc[mt][nt][r] *= alpha[mt][r];
                #pragma unroll
                for (int mt = 0; mt < 2; mt++)
                    #pragma unroll
                    for (int nt = 0; nt < 4; nt++)
                        #pragma unroll
                        for (int r = 0; r < 4; r++)
                            sP[(mt * 16 + quad * 4 + r) * PSTR + nt * 16 + ln] = f2b(Sc[mt][nt][r]);
                __builtin_amdgcn_s_setprio(1);
                #pragma unroll
                for (int kp = 0; kp < 2; kp++) {
                    bf16x8 ap[2];
                    #pragma unroll
                    for (int mt = 0; mt < 2; mt++)
                        ap[mt] = *(const bf16x8*)&sP[(mt * 16 + ln) * PSTR + kp * 32 + quad * 8];
                    #pragma unroll
                    for (int nt = 0; nt < 4; nt++) {
                        bf16x8 bv = *(const bf16x8*)&sVt[cur][(nt * 16 + ln) * 64 +
                                                              (((kp * 4 + quad) ^ (ln & 7)) * 8)];
                        #pragma unroll
                        for (int mt = 0; mt < 2; mt++)
                            Oacc[mt][nt] = MFMA16(ap[mt], bv, Oacc[mt][nt]);
                    }
                }
                __builtin_amdgcn_s_setprio(0);
            }
            asm volatile("s_barrier" ::: "memory");
        }

        #pragma unroll
        for (int mt = 0; mt < 2; mt++)
            #pragma unroll
            for (int nt = 0; nt < 4; nt++)
                #pragma unroll
                for (int r = 0; r < 4; r++) {
                    float o = Oacc[mt][nt][r] / l_run[mt][r];
                    int srow = q0 + wave * 32 + mt * 16 + quad * 4 + r;
                    size_t tok = (size_t)bb * 2048 + srow;
                    Ob[tok * 1024 + h * 64 + nt * 16 + ln] = f2b(o);
                }
    }
}

// ---------------------------------------------------------------------------
extern "C" void kernel_launch(void* const* d_in, const int* in_sizes, int n_in,
                              void* d_out, int out_size, void* d_ws, size_t ws_size,
                              hipStream_t stream) {
    const float* x          = (const float*)d_in[0];
    const float* ln_attn_w  = (const float*)d_in[1];
    const float* ln_attn_b  = (const float*)d_in[2];
    const float* attn_in_w  = (const float*)d_in[3];
    const float* attn_in_b  = (const float*)d_in[4];
    const float* attn_out_w = (const float*)d_in[5];
    const float* attn_out_b = (const float*)d_in[6];
    const float* ln1_w      = (const float*)d_in[7];
    const float* ln1_b      = (const float*)d_in[8];
    const float* ln2_w      = (const float*)d_in[9];
    const float* ln2_b      = (const float*)d_in[10];
    const float* inl_u_w    = (const float*)d_in[11];
    const float* inl_u_b    = (const float*)d_in[12];
    const float* inl_a_w    = (const float*)d_in[13];
    const float* inl_a_b    = (const float*)d_in[14];
    const float* inl_b_w    = (const float*)d_in[15];
    const float* inl_b_b    = (const float*)d_in[16];
    const float* inl_g_w    = (const float*)d_in[17];
    const float* inl_g_b    = (const float*)d_in[18];
    const float* ff1_w      = (const float*)d_in[19];
    const float* ff1_b      = (const float*)d_in[20];
    const float* ff2_w      = (const float*)d_in[21];
    const float* ff2_b      = (const float*)d_in[22];
    float* out = (float*)d_out;

    char* ws = (char*)d_ws;
    unsigned short* Wqkv  = (unsigned short*)(ws);
    unsigned short* Wout  = (unsigned short*)(ws + 6291456);
    unsigned short* Winl  = (unsigned short*)(ws + 8388608);
    unsigned short* Wff1  = (unsigned short*)(ws + 16777216);
    unsigned short* Wff2  = (unsigned short*)(ws + 25165824);
    unsigned short* xnb   = (unsigned short*)(ws + 33554432);   // 16MB: xn, later h
    unsigned short* qb    = (unsigned short*)(ws + 50331648);   // 16MB
    unsigned short* kb    = (unsigned short*)(ws + 67108864);   // 16MB
    unsigned short* vtb   = (unsigned short*)(ws + 83886080);   // 16MB
    unsigned short* attnb = (unsigned short*)(ws + 100663296);  // 16MB
    unsigned short* ctxb  = (unsigned short*)(ws + 117440512);  // 16MB
    float*          bias4 = (float*)(ws + 167772160);           // 16KB
    unsigned short* uabg  = (unsigned short*)(ws + 50331648);   // 64MB, reuses q/k/vt/attn
    unsigned short* ff1b  = (unsigned short*)(ws + 50331648);   // 64MB, reuses uabg

    // 1. fused weight conversion (one launch) + bias concat
    cvt_all<<<16384, 256, 0, stream>>>(attn_in_w, attn_out_w, inl_u_w, inl_a_w,
                                       inl_b_w, inl_g_w, ff1_w, ff2_w,
                                       Wqkv, Wout, Winl, Winl + 1048576,
                                       Winl + 2097152, Winl + 3145728, Wff1, Wff2);
    catbias_kernel<<<16, 256, 0, stream>>>(inl_u_b, inl_a_b, inl_b_b, inl_g_b, bias4);

    // 2. xn = LN(x)
    ln_kernel<<<8192, 256, 0, stream>>>(x, ln_attn_w, ln_attn_b, xnb);
    // 3. qkv projection, scattered into per-head q/k/v^T
    gemm_bt<0><<<dim3(24, 64), 256, 0, stream>>>(xnb, Wqkv, attn_in_b, 1024, qb, kb, vtb, nullptr, nullptr);
    // 4. causal flash attention (balanced pairs)
    attn_kernel<<<dim3(8, 64), 256, 0, stream>>>(qb, kb, vtb, attnb);
    // 5. out-projection: ctx (bf16) + x1 = x + ctx -> d_out
    gemm_bt<1><<<dim3(8, 64), 256, 0, stream>>>(attnb, Wout, attn_out_b, 1024, ctxb, nullptr, nullptr, out, x);
    // 6. fused INL controllers: u | sigmoid | softplus | sigmoid
    gemm_bt<2><<<dim3(32, 64), 256, 0, stream>>>(ctxb, Winl, bias4, 1024, uabg, nullptr, nullptr, nullptr, nullptr);
    // 7. FUSED ln1 + integrator + ln2: x2 -> d_out, h -> xnb
    integrator_ln_kernel<<<8192, 256, 0, stream>>>(ln1_w, ln1_b, ln2_w, ln2_b, uabg, out, xnb);
    // 8. FF1 + exact GELU
    gemm_bt<3><<<dim3(32, 64), 256, 0, stream>>>(xnb, Wff1, ff1_b, 1024, ff1b, nullptr, nullptr, nullptr, nullptr);
    // 9. FF2 + residual accumulate -> d_out
    gemm_bt<4><<<dim3(8, 64), 256, 0, stream>>>(ff1b, Wff2, ff2_b, 4096, nullptr, nullptr, nullptr, out, nullptr);
}

// Round 9
// 825.864 us; speedup vs baseline: 1.3862x; 1.0416x over previous
//
#include <hip/hip_runtime.h>
#include <cstdint>
#include <cmath>

typedef __attribute__((ext_vector_type(4))) float floatx4;
typedef __attribute__((ext_vector_type(8))) __bf16 bf16x8;
typedef __attribute__((ext_vector_type(4))) unsigned short ushort4v;

#define DEVI static __device__ __forceinline__

DEVI unsigned short f2b(float f) {
    unsigned x = __float_as_uint(f);
    return (unsigned short)((x + 0x7fffu + ((x >> 16) & 1u)) >> 16);
}
DEVI float b2f(unsigned short u) { return __uint_as_float(((unsigned)u) << 16); }

// async global->LDS, 16B per lane; LDS dest is wave-uniform base + lane*16
DEVI void load16(void* lds, const void* g) {
    __builtin_amdgcn_global_load_lds(
        (__attribute__((address_space(1))) void*)(const_cast<void*>(g)),
        (__attribute__((address_space(3))) void*)lds, 16, 0, 0);
}

DEVI floatx4 MFMA16(bf16x8 a, bf16x8 b, floatx4 c) {
    return __builtin_amdgcn_mfma_f32_16x16x32_bf16(a, b, c, 0, 0, 0);
}

// ---------------------------------------------------------------------------
// fused fp32 -> bf16 weight conversion: 16 segments of 262144 float4 (1MB)
// seg: [0,3)=Wqkv  3=Wout  4..7=Winl{u,a,b,g}  [8,12)=Wff1  [12,16)=Wff2
// ---------------------------------------------------------------------------
__global__ __launch_bounds__(256) void cvt_all(const float* __restrict__ s0,
                                               const float* __restrict__ s1,
                                               const float* __restrict__ s2,
                                               const float* __restrict__ s3,
                                               const float* __restrict__ s4,
                                               const float* __restrict__ s5,
                                               const float* __restrict__ s6,
                                               const float* __restrict__ s7,
                                               unsigned short* d0, unsigned short* d1,
                                               unsigned short* d2, unsigned short* d3,
                                               unsigned short* d4, unsigned short* d5,
                                               unsigned short* d6, unsigned short* d7) {
    int i = blockIdx.x * 256 + threadIdx.x;    // float4 index, 16*262144 total
    int seg = i >> 18;
    int j = i & 262143;
    const float* src; unsigned short* dst;
    if (seg < 3)        { src = s0; dst = d0; j += seg * 262144; }
    else if (seg == 3)  { src = s1; dst = d1; }
    else if (seg == 4)  { src = s2; dst = d2; }
    else if (seg == 5)  { src = s3; dst = d3; }
    else if (seg == 6)  { src = s4; dst = d4; }
    else if (seg == 7)  { src = s5; dst = d5; }
    else if (seg < 12)  { src = s6; dst = d6; j += (seg - 8) * 262144; }
    else                { src = s7; dst = d7; j += (seg - 12) * 262144; }
    floatx4 v = ((const floatx4*)src)[j];
    ushort4v o;
    o[0] = f2b(v[0]); o[1] = f2b(v[1]); o[2] = f2b(v[2]); o[3] = f2b(v[3]);
    ((ushort4v*)dst)[j] = o;
}

__global__ __launch_bounds__(256) void catbias_kernel(const float* __restrict__ a,
                                                      const float* __restrict__ b,
                                                      const float* __restrict__ c,
                                                      const float* __restrict__ d,
                                                      float* __restrict__ o) {
    int i = blockIdx.x * 256 + threadIdx.x;   // 4096 total
    int p = i >> 10, j = i & 1023;
    float v = (p == 0) ? a[j] : (p == 1) ? b[j] : (p == 2) ? c[j] : d[j];
    o[i] = v;
}

// ---------------------------------------------------------------------------
// LayerNorm over D=1024: one block per row, bf16 output (used for LN(x) only)
// ---------------------------------------------------------------------------
__global__ __launch_bounds__(256) void ln_kernel(const float* __restrict__ in,
                                                 const float* __restrict__ w,
                                                 const float* __restrict__ b,
                                                 unsigned short* __restrict__ obf) {
    const int row = blockIdx.x, tid = threadIdx.x;
    const floatx4* pr = (const floatx4*)(in + (size_t)row * 1024);
    floatx4 v = pr[tid];
    float s  = v[0] + v[1] + v[2] + v[3];
    float ss = v[0]*v[0] + v[1]*v[1] + v[2]*v[2] + v[3]*v[3];
    #pragma unroll
    for (int o = 32; o >= 1; o >>= 1) { s += __shfl_xor(s, o); ss += __shfl_xor(ss, o); }
    __shared__ float red[8];
    int wv = tid >> 6, lane = tid & 63;
    if (lane == 0) { red[wv] = s; red[4 + wv] = ss; }
    __syncthreads();
    s  = red[0] + red[1] + red[2] + red[3];
    ss = red[4] + red[5] + red[6] + red[7];
    float mu  = s * (1.0f / 1024.0f);
    float var = ss * (1.0f / 1024.0f) - mu * mu;
    float rstd = rsqrtf(var + 1e-5f);
    floatx4 wv4 = ((const floatx4*)w)[tid];
    floatx4 bv4 = ((const floatx4*)b)[tid];
    ushort4v t;
    #pragma unroll
    for (int c = 0; c < 4; c++) t[c] = f2b((v[c] - mu) * rstd * wv4[c] + bv4[c]);
    ((ushort4v*)(obf + (size_t)row * 1024))[tid] = t;
}

// ---------------------------------------------------------------------------
// FUSED ln1 + INL integrator + ln2 (one block = one token, 256 thr x 4 elems)
// ---------------------------------------------------------------------------
__global__ __launch_bounds__(256) void integrator_ln_kernel(const float* __restrict__ w1,
                                                            const float* __restrict__ b1,
                                                            const float* __restrict__ w2,
                                                            const float* __restrict__ b2,
                                                            const unsigned short* __restrict__ uabg,
                                                            float* __restrict__ xio,
                                                            unsigned short* __restrict__ hb) {
    const int row = blockIdx.x, tid = threadIdx.x;
    const int wv = tid >> 6, lane = tid & 63;
    __shared__ float red[8], red2[8];

    floatx4 v = ((const floatx4*)(xio + (size_t)row * 1024))[tid];
    float s  = v[0] + v[1] + v[2] + v[3];
    float ss = v[0]*v[0] + v[1]*v[1] + v[2]*v[2] + v[3]*v[3];
    #pragma unroll
    for (int o = 32; o >= 1; o >>= 1) { s += __shfl_xor(s, o); ss += __shfl_xor(ss, o); }
    if (lane == 0) { red[wv] = s; red[4 + wv] = ss; }
    __syncthreads();
    s  = red[0] + red[1] + red[2] + red[3];
    ss = red[4] + red[5] + red[6] + red[7];
    float mu  = s * (1.0f / 1024.0f);
    float rstd = rsqrtf(ss * (1.0f / 1024.0f) - mu * mu + 1e-5f);
    floatx4 w1v = ((const floatx4*)w1)[tid];
    floatx4 b1v = ((const floatx4*)b1)[tid];

    const unsigned short* ubase = uabg + (size_t)row * 4096 + tid * 4;
    ushort4v uu = *(const ushort4v*)(ubase);
    ushort4v aa = *(const ushort4v*)(ubase + 1024);
    ushort4v bb = *(const ushort4v*)(ubase + 2048);
    ushort4v gg = *(const ushort4v*)(ubase + 3072);
    floatx4 res;
    #pragma unroll
    for (int c = 0; c < 4; c++) {
        float xs = (v[c] - mu) * rstd * w1v[c] + b1v[c];
        float u = b2f(uu[c]), a = b2f(aa[c]), bt = b2f(bb[c]), g = b2f(gg[c]);
        float vs = 0.f;
        #pragma unroll
        for (int t = 0; t < 5; t++) {
            vs += 0.1f * (-a * xs - bt * vs + u);
            xs += 0.1f * g * vs;
        }
        res[c] = v[c] + xs;
    }
    ((floatx4*)(xio + (size_t)row * 1024))[tid] = res;   // x2

    float s2  = res[0] + res[1] + res[2] + res[3];
    float ss2 = res[0]*res[0] + res[1]*res[1] + res[2]*res[2] + res[3]*res[3];
    #pragma unroll
    for (int o = 32; o >= 1; o >>= 1) { s2 += __shfl_xor(s2, o); ss2 += __shfl_xor(ss2, o); }
    if (lane == 0) { red2[wv] = s2; red2[4 + wv] = ss2; }
    __syncthreads();
    s2  = red2[0] + red2[1] + red2[2] + red2[3];
    ss2 = red2[4] + red2[5] + red2[6] + red2[7];
    float mu2  = s2 * (1.0f / 1024.0f);
    float rstd2 = rsqrtf(ss2 * (1.0f / 1024.0f) - mu2 * mu2 + 1e-5f);
    floatx4 w2v = ((const floatx4*)w2)[tid];
    floatx4 b2v = ((const floatx4*)b2)[tid];
    ushort4v t;
    #pragma unroll
    for (int c = 0; c < 4; c++) t[c] = f2b((res[c] - mu2) * rstd2 * w2v[c] + b2v[c]);
    ((ushort4v*)(hb + (size_t)row * 1024))[tid] = t;
}

// ---------------------------------------------------------------------------
// bf16 GEMM v7: 128x128 tile, **BK=64**, 4 waves (2x2 of 64x64), 2-buf LDS.
// Tests the last unfalsified hypothesis: per-barrier-step fixed cost.
// Halves the barrier count (T=K/64) at 2x work per step; one barrier + one
// vmcnt(0) per step.  All building blocks previously verified:
//  - staging layout [rows][64] + both-sides swizzle g_phys=g_log^(row&7):
//    source col pre-swizzled ((tid&7)^((tid>>3)&7)), LDS dest LINEAR
//    (gemm2p/R4 convention — passed, 0 read conflicts).
//  - fragment reads per K-half kk: granule (quad+4kk)^(ln&7) (gemm2p R4).
//  - 2-buf / stage-1-ahead liveness (R5): reads of buf c drain (lgkm0)
//    before the end-of-step barrier; writes to c^1 drain (vmcnt0) before it.
// LDS 64KB -> 2 blocks/CU (R5 showed occupancy ~neutral 2..4).
// EPI: 0=QKV scatter  1=out-proj(+residual,+ctx)  2=INL activations
//      3=FF1 GELU     4=FF2 accumulate into d_out
// ---------------------------------------------------------------------------
template <int EPI>
__global__ __launch_bounds__(256, 2) void gemm_bt(const unsigned short* __restrict__ A,
                                                  const unsigned short* __restrict__ W,
                                                  const float* __restrict__ bias, int K,
                                                  unsigned short* __restrict__ ob0,
                                                  unsigned short* __restrict__ ob1,
                                                  unsigned short* __restrict__ ob2,
                                                  float* __restrict__ of0,
                                                  const float* __restrict__ xres) {
    __shared__ unsigned short sA[2][128 * 64];
    __shared__ unsigned short sB[2][128 * 64];
    const int tid = threadIdx.x;
    const int wave = tid >> 6, lane = tid & 63;
    const int ln = lane & 15, quad = lane >> 4;
    const size_t m0 = (size_t)blockIdx.y * 128;
    const int n0 = blockIdx.x * 128;
    const int wm = (wave >> 1) * 64, wn = (wave & 1) * 64;

    const floatx4 z4 = {0.f, 0.f, 0.f, 0.f};
    floatx4 acc[4][4];
    #pragma unroll
    for (int mt = 0; mt < 4; mt++)
        #pragma unroll
        for (int nt = 0; nt < 4; nt++) acc[mt][nt] = z4;

    // staging: thread tid -> row tid>>3 (+32 per j), source col pre-swizzled
    // so linear LDS dest realizes g_phys = g_log ^ (row&7).
    const int srow = tid >> 3;                        // 0..31
    const int ssw  = ((tid & 7) ^ (srow & 7)) * 8;    // source col (ushorts)
    const unsigned short* gA = A + (m0 + srow) * K + ssw;
    const unsigned short* gB = W + ((size_t)(n0 + srow)) * K + ssw;
    const size_t rs32 = (size_t)32 * K;
    const int lwb = wave * 512;                       // wave rows w*8.. (x64 cols)

    auto stage = [&](int buf, int t) {
        const unsigned short* a = gA + (size_t)t * 64;
        const unsigned short* b = gB + (size_t)t * 64;
        #pragma unroll
        for (int j = 0; j < 4; j++) {
            load16(&sA[buf][j * 2048 + lwb], a + j * rs32);
            load16(&sB[buf][j * 2048 + lwb], b + j * rs32);
        }
    };

    // fragment reads: row-major [128][64]; K-half kk granule (quad+4kk)^(ln&7)
    const int lnx = ln & 7;
    const int ga0 = (quad ^ lnx) * 8;
    const int ga1 = ((quad + 4) ^ lnx) * 8;
    bf16x8 fa[4], fb[4];
    auto ldfrag = [&](int buf, int ga) {
        #pragma unroll
        for (int mt = 0; mt < 4; mt++)
            fa[mt] = *(const bf16x8*)&sA[buf][(wm + mt * 16 + ln) * 64 + ga];
        #pragma unroll
        for (int nt = 0; nt < 4; nt++)
            fb[nt] = *(const bf16x8*)&sB[buf][(wn + nt * 16 + ln) * 64 + ga];
    };
    auto mmah = [&]() {
        __builtin_amdgcn_s_setprio(1);
        #pragma unroll
        for (int mt = 0; mt < 4; mt++)
            #pragma unroll
            for (int nt = 0; nt < 4; nt++)
                acc[mt][nt] = MFMA16(fa[mt], fb[nt], acc[mt][nt]);
        __builtin_amdgcn_s_setprio(0);
    };

    const int T = K >> 6;

    // prologue: tile 0 -> buf 0
    stage(0, 0);
    asm volatile("s_waitcnt vmcnt(0)" ::: "memory");
    asm volatile("s_barrier" ::: "memory");

    #pragma unroll 1
    for (int t = 0; t < T; t++) {
        const int c = t & 1;
        if (t + 1 < T) stage(c ^ 1, t + 1);
        __builtin_amdgcn_sched_barrier(0);
        // K-half 0
        ldfrag(c, ga0);
        asm volatile("s_waitcnt lgkmcnt(0)" ::: "memory");
        __builtin_amdgcn_sched_barrier(0);
        mmah();
        // K-half 1
        ldfrag(c, ga1);
        asm volatile("s_waitcnt lgkmcnt(0)" ::: "memory");
        __builtin_amdgcn_sched_barrier(0);
        mmah();
        __builtin_amdgcn_sched_barrier(0);
        if (t + 1 < T) {
            asm volatile("s_waitcnt vmcnt(0)" ::: "memory");
            asm volatile("s_barrier" ::: "memory");
        }
    }

    // epilogue: C/D layout col=lane&15, row=(lane>>4)*4+reg  [verified m89/m91]
    const size_t rowb = m0 + wm + quad * 4;
    const int colb = n0 + wn + ln;
    #pragma unroll
    for (int mt = 0; mt < 4; mt++) {
        #pragma unroll
        for (int nt = 0; nt < 4; nt++) {
            const int n = colb + nt * 16;
            const float bs = bias[n];
            #pragma unroll
            for (int r = 0; r < 4; r++) {
                const size_t row = rowb + mt * 16 + r;
                float c = acc[mt][nt][r] + bs;
                if constexpr (EPI == 0) {
                    int sect = n >> 10, d1 = n & 1023, h = d1 >> 6, d = d1 & 63;
                    int bb = (int)(row >> 11), s = (int)(row & 2047);
                    size_t bh = (size_t)(bb * 16 + h);
                    if (sect == 0)      ob0[(bh * 2048 + s) * 64 + d] = f2b(c);
                    else if (sect == 1) ob1[(bh * 2048 + s) * 64 + d] = f2b(c);
                    else                ob2[(bh * 64 + d) * 2048 + s] = f2b(c);  // V^T
                } else if constexpr (EPI == 1) {
                    size_t idx = row * 1024 + n;
                    ob0[idx] = f2b(c);                 // ctx (pre-residual) for INL
                    of0[idx] = xres[idx] + c;          // x1 = x + attn_out
                } else if constexpr (EPI == 2) {
                    int p = n >> 10;
                    float v;
                    if (p == 0)       v = c;                                            // u
                    else if (p == 2)  v = fmaxf(c, 0.f) + log1pf(__expf(-fabsf(c)));    // softplus
                    else              v = 1.f / (1.f + __expf(-c));                     // sigmoid
                    ob0[row * 4096 + n] = f2b(v);
                } else if constexpr (EPI == 3) {
                    float v = 0.5f * c * (1.f + erff(c * 0.70710678118654752f));        // exact GELU
                    ob0[row * 4096 + n] = f2b(v);
                } else {
                    size_t idx = row * 1024 + n;
                    of0[idx] += c;                     // final residual accumulate
                }
            }
        }
    }
}

// ---------------------------------------------------------------------------
// Flash causal attention (+ setprio around MFMA clusters).
// ---------------------------------------------------------------------------
#define PSTR 72
__global__ __launch_bounds__(256, 3) void attn_kernel(const unsigned short* __restrict__ Qb,
                                                      const unsigned short* __restrict__ Kb,
                                                      const unsigned short* __restrict__ Vtb,
                                                      unsigned short* __restrict__ Ob) {
    __shared__ unsigned short sK[2][64 * 64];
    __shared__ unsigned short sVt[2][64 * 64];
    __shared__ unsigned short sQP[128 * PSTR];
    const int pr = blockIdx.x;
    const int bh = blockIdx.y;
    const int tid = threadIdx.x, wave = tid >> 6, lane = tid & 63;
    const int ln = lane & 15, quad = lane >> 4;
    const unsigned short* Q  = Qb  + (size_t)bh * 2048 * 64;
    const unsigned short* Kp = Kb  + (size_t)bh * 2048 * 64;
    const unsigned short* Vt = Vtb + (size_t)bh * 64 * 2048;

    const int rl  = lane >> 3;
    const int gsw = (((lane & 7) ^ rl)) * 8;
    const int sseg = wave * 2;
    const unsigned short* kbase = Kp + (size_t)(sseg * 8 + rl) * 64 + gsw;
    const unsigned short* vbase = Vt + (size_t)(sseg * 8 + rl) * 2048 + gsw;
    unsigned short* sP = &sQP[wave * 32 * PSTR];
    const int bb = bh >> 4, h = bh & 15;
    const floatx4 z4 = {0.f, 0.f, 0.f, 0.f};

    #pragma unroll 1
    for (int phase = 0; phase < 2; phase++) {
        const int qt = phase ? pr : (15 - pr);
        const int q0 = qt * 128;
        const int T = 2 * qt + 2;

        #pragma unroll
        for (int i = 0; i < 4; i++) {
            int s = wave * 4 + i;
            load16(&sQP[s * 512], Q + (size_t)(q0 + s * 8 + rl) * 64 + gsw);
        }
        load16(&sK[0][sseg * 512], kbase);
        load16(&sK[0][(sseg + 1) * 512], kbase + (size_t)8 * 64);
        load16(&sVt[0][sseg * 512], vbase);
        load16(&sVt[0][(sseg + 1) * 512], vbase + (size_t)8 * 2048);
        asm volatile("s_waitcnt vmcnt(0)" ::: "memory");
        asm volatile("s_barrier" ::: "memory");

        bf16x8 aq[2][2];
        #pragma unroll
        for (int mt = 0; mt < 2; mt++)
            #pragma unroll
            for (int ks = 0; ks < 2; ks++)
                aq[mt][ks] = *(const bf16x8*)&sQP[(wave * 32 + mt * 16 + ln) * 64 +
                                                  (((ks * 4 + quad) ^ (ln & 7)) * 8)];
        asm volatile("s_waitcnt lgkmcnt(0)" ::: "memory");
        asm volatile("s_barrier" ::: "memory");

        floatx4 Oacc[2][4];
        float m_run[2][4], l_run[2][4];
        #pragma unroll
        for (int mt = 0; mt < 2; mt++)
            #pragma unroll
            for (int j = 0; j < 4; j++) { Oacc[mt][j] = z4; m_run[mt][j] = -1e30f; l_run[mt][j] = 0.f; }

        const int wave_first = q0 + wave * 32;
        const int wave_last  = wave_first + 31;

        #pragma unroll 1
        for (int t = 0; t < T; t++) {
            const int kk0 = t * 64;
            const int cur = t & 1;
            if (t + 1 < T) {
                const unsigned short* kg = kbase + (size_t)(kk0 + 64) * 64;
                const unsigned short* vg = vbase + (size_t)(kk0 + 64);
                load16(&sK[cur ^ 1][sseg * 512], kg);
                load16(&sK[cur ^ 1][(sseg + 1) * 512], kg + (size_t)8 * 64);
                load16(&sVt[cur ^ 1][sseg * 512], vg);
                load16(&sVt[cur ^ 1][(sseg + 1) * 512], vg + (size_t)8 * 2048);
                asm volatile("s_waitcnt vmcnt(4)" ::: "memory");
            } else {
                asm volatile("s_waitcnt vmcnt(0)" ::: "memory");
            }
            asm volatile("s_barrier" ::: "memory");

            if (kk0 <= wave_last) {
                floatx4 Sc[2][4];
                #pragma unroll
                for (int mt = 0; mt < 2; mt++)
                    #pragma unroll
                    for (int nt = 0; nt < 4; nt++) Sc[mt][nt] = z4;
                __builtin_amdgcn_s_setprio(1);
                #pragma unroll
                for (int ks = 0; ks < 2; ks++) {
                    #pragma unroll
                    for (int nt = 0; nt < 4; nt++) {
                        bf16x8 bk = *(const bf16x8*)&sK[cur][(nt * 16 + ln) * 64 +
                                                             (((ks * 4 + quad) ^ (ln & 7)) * 8)];
                        #pragma unroll
                        for (int mt = 0; mt < 2; mt++)
                            Sc[mt][nt] = MFMA16(aq[mt][ks], bk, Sc[mt][nt]);
                    }
                }
                __builtin_amdgcn_s_setprio(0);
                const bool diag = (kk0 + 63 > wave_first);
                #pragma unroll
                for (int mt = 0; mt < 2; mt++)
                    #pragma unroll
                    for (int nt = 0; nt < 4; nt++)
                        #pragma unroll
                        for (int r = 0; r < 4; r++) {
                            float v = Sc[mt][nt][r] * 0.125f;
                            if (diag) {
                                int rowg = wave_first + mt * 16 + quad * 4 + r;
                                int colg = kk0 + nt * 16 + ln;
                                if (colg > rowg) v = -1e30f;
                            }
                            Sc[mt][nt][r] = v;
                        }
                float alpha[2][4];
                #pragma unroll
                for (int mt = 0; mt < 2; mt++)
                    #pragma unroll
                    for (int r = 0; r < 4; r++) {
                        float mx = fmaxf(fmaxf(Sc[mt][0][r], Sc[mt][1][r]), fmaxf(Sc[mt][2][r], Sc[mt][3][r]));
                        #pragma unroll
                        for (int off = 1; off < 16; off <<= 1) mx = fmaxf(mx, __shfl_xor(mx, off));
                        float mnew = fmaxf(m_run[mt][r], mx);
                        alpha[mt][r] = __expf(m_run[mt][r] - mnew);
                        m_run[mt][r] = mnew;
                    }
                #pragma unroll
                for (int mt = 0; mt < 2; mt++)
                    #pragma unroll
                    for (int r = 0; r < 4; r++) {
                        float rs = 0.f;
                        #pragma unroll
                        for (int nt = 0; nt < 4; nt++) {
                            float p = __expf(Sc[mt][nt][r] - m_run[mt][r]);
                            Sc[mt][nt][r] = p;
                            rs += p;
                        }
                        #pragma unroll
                        for (int off = 1; off < 16; off <<= 1) rs += __shfl_xor(rs, off);
                        l_run[mt][r] = l_run[mt][r] * alpha[mt][r] + rs;
                    }
                #pragma unroll
                for (int mt = 0; mt < 2; mt++)
                    #pragma unroll
                    for (int nt = 0; nt < 4; nt++)
                        #pragma unroll
                        for (int r = 0; r < 4; r++) Oacc[mt][nt][r] *= alpha[mt][r];
                #pragma unroll
                for (int mt = 0; mt < 2; mt++)
                    #pragma unroll
                    for (int nt = 0; nt < 4; nt++)
                        #pragma unroll
                        for (int r = 0; r < 4; r++)
                            sP[(mt * 16 + quad * 4 + r) * PSTR + nt * 16 + ln] = f2b(Sc[mt][nt][r]);
                __builtin_amdgcn_s_setprio(1);
                #pragma unroll
                for (int kp = 0; kp < 2; kp++) {
                    bf16x8 ap[2];
                    #pragma unroll
                    for (int mt = 0; mt < 2; mt++)
                        ap[mt] = *(const bf16x8*)&sP[(mt * 16 + ln) * PSTR + kp * 32 + quad * 8];
                    #pragma unroll
                    for (int nt = 0; nt < 4; nt++) {
                        bf16x8 bv = *(const bf16x8*)&sVt[cur][(nt * 16 + ln) * 64 +
                                                              (((kp * 4 + quad) ^ (ln & 7)) * 8)];
                        #pragma unroll
                        for (int mt = 0; mt < 2; mt++)
                            Oacc[mt][nt] = MFMA16(ap[mt], bv, Oacc[mt][nt]);
                    }
                }
                __builtin_amdgcn_s_setprio(0);
            }
            asm volatile("s_barrier" ::: "memory");
        }

        #pragma unroll
        for (int mt = 0; mt < 2; mt++)
            #pragma unroll
            for (int nt = 0; nt < 4; nt++)
                #pragma unroll
                for (int r = 0; r < 4; r++) {
                    float o = Oacc[mt][nt][r] / l_run[mt][r];
                    int srow = q0 + wave * 32 + mt * 16 + quad * 4 + r;
                    size_t tok = (size_t)bb * 2048 + srow;
                    Ob[tok * 1024 + h * 64 + nt * 16 + ln] = f2b(o);
                }
    }
}

// ---------------------------------------------------------------------------
extern "C" void kernel_launch(void* const* d_in, const int* in_sizes, int n_in,
                              void* d_out, int out_size, void* d_ws, size_t ws_size,
                              hipStream_t stream) {
    const float* x          = (const float*)d_in[0];
    const float* ln_attn_w  = (const float*)d_in[1];
    const float* ln_attn_b  = (const float*)d_in[2];
    const float* attn_in_w  = (const float*)d_in[3];
    const float* attn_in_b  = (const float*)d_in[4];
    const float* attn_out_w = (const float*)d_in[5];
    const float* attn_out_b = (const float*)d_in[6];
    const float* ln1_w      = (const float*)d_in[7];
    const float* ln1_b      = (const float*)d_in[8];
    const float* ln2_w      = (const float*)d_in[9];
    const float* ln2_b      = (const float*)d_in[10];
    const float* inl_u_w    = (const float*)d_in[11];
    const float* inl_u_b    = (const float*)d_in[12];
    const float* inl_a_w    = (const float*)d_in[13];
    const float* inl_a_b    = (const float*)d_in[14];
    const float* inl_b_w    = (const float*)d_in[15];
    const float* inl_b_b    = (const float*)d_in[16];
    const float* inl_g_w    = (const float*)d_in[17];
    const float* inl_g_b    = (const float*)d_in[18];
    const float* ff1_w      = (const float*)d_in[19];
    const float* ff1_b      = (const float*)d_in[20];
    const float* ff2_w      = (const float*)d_in[21];
    const float* ff2_b      = (const float*)d_in[22];
    float* out = (float*)d_out;

    char* ws = (char*)d_ws;
    unsigned short* Wqkv  = (unsigned short*)(ws);
    unsigned short* Wout  = (unsigned short*)(ws + 6291456);
    unsigned short* Winl  = (unsigned short*)(ws + 8388608);
    unsigned short* Wff1  = (unsigned short*)(ws + 16777216);
    unsigned short* Wff2  = (unsigned short*)(ws + 25165824);
    unsigned short* xnb   = (unsigned short*)(ws + 33554432);   // 16MB: xn, later h
    unsigned short* qb    = (unsigned short*)(ws + 50331648);   // 16MB
    unsigned short* kb    = (unsigned short*)(ws + 67108864);   // 16MB
    unsigned short* vtb   = (unsigned short*)(ws + 83886080);   // 16MB
    unsigned short* attnb = (unsigned short*)(ws + 100663296);  // 16MB
    unsigned short* ctxb  = (unsigned short*)(ws + 117440512);  // 16MB
    float*          bias4 = (float*)(ws + 167772160);           // 16KB
    unsigned short* uabg  = (unsigned short*)(ws + 50331648);   // 64MB, reuses q/k/vt/attn
    unsigned short* ff1b  = (unsigned short*)(ws + 50331648);   // 64MB, reuses uabg

    // 1. fused weight conversion (one launch) + bias concat
    cvt_all<<<16384, 256, 0, stream>>>(attn_in_w, attn_out_w, inl_u_w, inl_a_w,
                                       inl_b_w, inl_g_w, ff1_w, ff2_w,
                                       Wqkv, Wout, Winl, Winl + 1048576,
                                       Winl + 2097152, Winl + 3145728, Wff1, Wff2);
    catbias_kernel<<<16, 256, 0, stream>>>(inl_u_b, inl_a_b, inl_b_b, inl_g_b, bias4);

    // 2. xn = LN(x)
    ln_kernel<<<8192, 256, 0, stream>>>(x, ln_attn_w, ln_attn_b, xnb);
    // 3. qkv projection, scattered into per-head q/k/v^T
    gemm_bt<0><<<dim3(24, 64), 256, 0, stream>>>(xnb, Wqkv, attn_in_b, 1024, qb, kb, vtb, nullptr, nullptr);
    // 4. causal flash attention (balanced pairs)
    attn_kernel<<<dim3(8, 64), 256, 0, stream>>>(qb, kb, vtb, attnb);
    // 5. out-projection: ctx (bf16) + x1 = x + ctx -> d_out
    gemm_bt<1><<<dim3(8, 64), 256, 0, stream>>>(attnb, Wout, attn_out_b, 1024, ctxb, nullptr, nullptr, out, x);
    // 6. fused INL controllers: u | sigmoid | softplus | sigmoid
    gemm_bt<2><<<dim3(32, 64), 256, 0, stream>>>(ctxb, Winl, bias4, 1024, uabg, nullptr, nullptr, nullptr, nullptr);
    // 7. FUSED ln1 + integrator + ln2: x2 -> d_out, h -> xnb
    integrator_ln_kernel<<<8192, 256, 0, stream>>>(ln1_w, ln1_b, ln2_w, ln2_b, uabg, out, xnb);
    // 8. FF1 + exact GELU
    gemm_bt<3><<<dim3(32, 64), 256, 0, stream>>>(xnb, Wff1, ff1_b, 1024, ff1b, nullptr, nullptr, nullptr, nullptr);
    // 9. FF2 + residual accumulate -> d_out
    gemm_bt<4><<<dim3(8, 64), 256, 0, stream>>>(ff1b, Wff2, ff2_b, 4096, nullptr, nullptr, nullptr, out, nullptr);
}

// Round 10
// 793.970 us; speedup vs baseline: 1.4419x; 1.0402x over previous
//
#include <hip/hip_runtime.h>
#include <cstdint>
#include <cmath>

typedef __attribute__((ext_vector_type(4))) float floatx4;
typedef __attribute__((ext_vector_type(8))) __bf16 bf16x8;
typedef __attribute__((ext_vector_type(4))) unsigned short ushort4v;

#define DEVI static __device__ __forceinline__

DEVI unsigned short f2b(float f) {
    unsigned x = __float_as_uint(f);
    return (unsigned short)((x + 0x7fffu + ((x >> 16) & 1u)) >> 16);
}
DEVI float b2f(unsigned short u) { return __uint_as_float(((unsigned)u) << 16); }

// async global->LDS, 16B per lane; LDS dest is wave-uniform base + lane*16
DEVI void load16(void* lds, const void* g) {
    __builtin_amdgcn_global_load_lds(
        (__attribute__((address_space(1))) void*)(const_cast<void*>(g)),
        (__attribute__((address_space(3))) void*)lds, 16, 0, 0);
}

DEVI floatx4 MFMA16(bf16x8 a, bf16x8 b, floatx4 c) {
    return __builtin_amdgcn_mfma_f32_16x16x32_bf16(a, b, c, 0, 0, 0);
}

// ---------------------------------------------------------------------------
// fused fp32 -> bf16 weight conversion: 16 segments of 262144 float4 (1MB)
// ---------------------------------------------------------------------------
__global__ __launch_bounds__(256) void cvt_all(const float* __restrict__ s0,
                                               const float* __restrict__ s1,
                                               const float* __restrict__ s2,
                                               const float* __restrict__ s3,
                                               const float* __restrict__ s4,
                                               const float* __restrict__ s5,
                                               const float* __restrict__ s6,
                                               const float* __restrict__ s7,
                                               unsigned short* d0, unsigned short* d1,
                                               unsigned short* d2, unsigned short* d3,
                                               unsigned short* d4, unsigned short* d5,
                                               unsigned short* d6, unsigned short* d7) {
    int i = blockIdx.x * 256 + threadIdx.x;    // float4 index, 16*262144 total
    int seg = i >> 18;
    int j = i & 262143;
    const float* src; unsigned short* dst;
    if (seg < 3)        { src = s0; dst = d0; j += seg * 262144; }
    else if (seg == 3)  { src = s1; dst = d1; }
    else if (seg == 4)  { src = s2; dst = d2; }
    else if (seg == 5)  { src = s3; dst = d3; }
    else if (seg == 6)  { src = s4; dst = d4; }
    else if (seg == 7)  { src = s5; dst = d5; }
    else if (seg < 12)  { src = s6; dst = d6; j += (seg - 8) * 262144; }
    else                { src = s7; dst = d7; j += (seg - 12) * 262144; }
    floatx4 v = ((const floatx4*)src)[j];
    ushort4v o;
    o[0] = f2b(v[0]); o[1] = f2b(v[1]); o[2] = f2b(v[2]); o[3] = f2b(v[3]);
    ((ushort4v*)dst)[j] = o;
}

__global__ __launch_bounds__(256) void catbias_kernel(const float* __restrict__ a,
                                                      const float* __restrict__ b,
                                                      const float* __restrict__ c,
                                                      const float* __restrict__ d,
                                                      float* __restrict__ o) {
    int i = blockIdx.x * 256 + threadIdx.x;   // 4096 total
    int p = i >> 10, j = i & 1023;
    float v = (p == 0) ? a[j] : (p == 1) ? b[j] : (p == 2) ? c[j] : d[j];
    o[i] = v;
}

// ---------------------------------------------------------------------------
// LayerNorm over D=1024: one block per row, bf16 output (used for LN(x) only)
// ---------------------------------------------------------------------------
__global__ __launch_bounds__(256) void ln_kernel(const float* __restrict__ in,
                                                 const float* __restrict__ w,
                                                 const float* __restrict__ b,
                                                 unsigned short* __restrict__ obf) {
    const int row = blockIdx.x, tid = threadIdx.x;
    const floatx4* pr = (const floatx4*)(in + (size_t)row * 1024);
    floatx4 v = pr[tid];
    float s  = v[0] + v[1] + v[2] + v[3];
    float ss = v[0]*v[0] + v[1]*v[1] + v[2]*v[2] + v[3]*v[3];
    #pragma unroll
    for (int o = 32; o >= 1; o >>= 1) { s += __shfl_xor(s, o); ss += __shfl_xor(ss, o); }
    __shared__ float red[8];
    int wv = tid >> 6, lane = tid & 63;
    if (lane == 0) { red[wv] = s; red[4 + wv] = ss; }
    __syncthreads();
    s  = red[0] + red[1] + red[2] + red[3];
    ss = red[4] + red[5] + red[6] + red[7];
    float mu  = s * (1.0f / 1024.0f);
    float var = ss * (1.0f / 1024.0f) - mu * mu;
    float rstd = rsqrtf(var + 1e-5f);
    floatx4 wv4 = ((const floatx4*)w)[tid];
    floatx4 bv4 = ((const floatx4*)b)[tid];
    ushort4v t;
    #pragma unroll
    for (int c = 0; c < 4; c++) t[c] = f2b((v[c] - mu) * rstd * wv4[c] + bv4[c]);
    ((ushort4v*)(obf + (size_t)row * 1024))[tid] = t;
}

// ---------------------------------------------------------------------------
// FUSED ln1 + INL integrator + ln2 (one block = one token, 256 thr x 4 elems)
// ---------------------------------------------------------------------------
__global__ __launch_bounds__(256) void integrator_ln_kernel(const float* __restrict__ w1,
                                                            const float* __restrict__ b1,
                                                            const float* __restrict__ w2,
                                                            const float* __restrict__ b2,
                                                            const unsigned short* __restrict__ uabg,
                                                            float* __restrict__ xio,
                                                            unsigned short* __restrict__ hb) {
    const int row = blockIdx.x, tid = threadIdx.x;
    const int wv = tid >> 6, lane = tid & 63;
    __shared__ float red[8], red2[8];

    floatx4 v = ((const floatx4*)(xio + (size_t)row * 1024))[tid];
    float s  = v[0] + v[1] + v[2] + v[3];
    float ss = v[0]*v[0] + v[1]*v[1] + v[2]*v[2] + v[3]*v[3];
    #pragma unroll
    for (int o = 32; o >= 1; o >>= 1) { s += __shfl_xor(s, o); ss += __shfl_xor(ss, o); }
    if (lane == 0) { red[wv] = s; red[4 + wv] = ss; }
    __syncthreads();
    s  = red[0] + red[1] + red[2] + red[3];
    ss = red[4] + red[5] + red[6] + red[7];
    float mu  = s * (1.0f / 1024.0f);
    float rstd = rsqrtf(ss * (1.0f / 1024.0f) - mu * mu + 1e-5f);
    floatx4 w1v = ((const floatx4*)w1)[tid];
    floatx4 b1v = ((const floatx4*)b1)[tid];

    const unsigned short* ubase = uabg + (size_t)row * 4096 + tid * 4;
    ushort4v uu = *(const ushort4v*)(ubase);
    ushort4v aa = *(const ushort4v*)(ubase + 1024);
    ushort4v bb = *(const ushort4v*)(ubase + 2048);
    ushort4v gg = *(const ushort4v*)(ubase + 3072);
    floatx4 res;
    #pragma unroll
    for (int c = 0; c < 4; c++) {
        float xs = (v[c] - mu) * rstd * w1v[c] + b1v[c];
        float u = b2f(uu[c]), a = b2f(aa[c]), bt = b2f(bb[c]), g = b2f(gg[c]);
        float vs = 0.f;
        #pragma unroll
        for (int t = 0; t < 5; t++) {
            vs += 0.1f * (-a * xs - bt * vs + u);
            xs += 0.1f * g * vs;
        }
        res[c] = v[c] + xs;
    }
    ((floatx4*)(xio + (size_t)row * 1024))[tid] = res;   // x2

    float s2  = res[0] + res[1] + res[2] + res[3];
    float ss2 = res[0]*res[0] + res[1]*res[1] + res[2]*res[2] + res[3]*res[3];
    #pragma unroll
    for (int o = 32; o >= 1; o >>= 1) { s2 += __shfl_xor(s2, o); ss2 += __shfl_xor(ss2, o); }
    if (lane == 0) { red2[wv] = s2; red2[4 + wv] = ss2; }
    __syncthreads();
    s2  = red2[0] + red2[1] + red2[2] + red2[3];
    ss2 = red2[4] + red2[5] + red2[6] + red2[7];
    float mu2  = s2 * (1.0f / 1024.0f);
    float rstd2 = rsqrtf(ss2 * (1.0f / 1024.0f) - mu2 * mu2 + 1e-5f);
    floatx4 w2v = ((const floatx4*)w2)[tid];
    floatx4 b2v = ((const floatx4*)b2)[tid];
    ushort4v t;
    #pragma unroll
    for (int c = 0; c < 4; c++) t[c] = f2b((res[c] - mu2) * rstd2 * w2v[c] + b2v[c]);
    ((ushort4v*)(hb + (size_t)row * 1024))[tid] = t;
}

// ---------------------------------------------------------------------------
// gemm32: 128x128 tile, BK=32, 3-buf LDS + reg-dbuf frags (R8 config —
// best measured at K=1024: 173 us).  Used for EPI 0,1,2,3.
// ---------------------------------------------------------------------------
template <int EPI>
__global__ __launch_bounds__(256, 3) void gemm32(const unsigned short* __restrict__ A,
                                                 const unsigned short* __restrict__ W,
                                                 const float* __restrict__ bias, int K,
                                                 unsigned short* __restrict__ ob0,
                                                 unsigned short* __restrict__ ob1,
                                                 unsigned short* __restrict__ ob2,
                                                 float* __restrict__ of0,
                                                 const float* __restrict__ xres) {
    __shared__ unsigned short sA[3][128 * 32];
    __shared__ unsigned short sB[3][128 * 32];
    const int tid = threadIdx.x;
    const int wave = tid >> 6, lane = tid & 63;
    const int ln = lane & 15, quad = lane >> 4;
    const size_t m0 = (size_t)blockIdx.y * 128;
    const int n0 = blockIdx.x * 128;
    const int wm = (wave >> 1) * 64, wn = (wave & 1) * 64;

    const floatx4 z4 = {0.f, 0.f, 0.f, 0.f};
    floatx4 acc[4][4];
    #pragma unroll
    for (int mt = 0; mt < 4; mt++)
        #pragma unroll
        for (int nt = 0; nt < 4; nt++) acc[mt][nt] = z4;

    const int r16 = lane >> 2;
    const int gsw = (((lane & 3) ^ (r16 & 3) ^ ((r16 >> 2) & 3))) * 8;
    const int arow = wave * 16 + r16;
    const unsigned short* gA = A + (m0 + (size_t)arow) * K + gsw;
    const unsigned short* gB = W + ((size_t)(n0 + arow)) * K + gsw;
    const size_t rs64 = (size_t)64 * K;
    const int so = wave * 512;
    const int swr = ((quad ^ (ln & 3) ^ ((ln >> 2) & 3))) * 8;

    const int T = K >> 5;

    load16(&sA[0][so], gA);
    load16(&sA[0][so + 2048], gA + rs64);
    load16(&sB[0][so], gB);
    load16(&sB[0][so + 2048], gB + rs64);
    load16(&sA[1][so], gA + 32);
    load16(&sA[1][so + 2048], gA + rs64 + 32);
    load16(&sB[1][so], gB + 32);
    load16(&sB[1][so + 2048], gB + rs64 + 32);
    asm volatile("s_waitcnt vmcnt(4)" ::: "memory");
    asm volatile("s_barrier" ::: "memory");

    bf16x8 fa0[4], fb0[4], fa1[4], fb1[4];
    #pragma unroll
    for (int mt = 0; mt < 4; mt++)
        fa0[mt] = *(const bf16x8*)&sA[0][(wm + mt * 16 + ln) * 32 + swr];
    #pragma unroll
    for (int nt = 0; nt < 4; nt++)
        fb0[nt] = *(const bf16x8*)&sB[0][(wn + nt * 16 + ln) * 32 + swr];

    auto step = [&](int t, bf16x8* afc, bf16x8* bfc, bf16x8* afn, bf16x8* bfn) {
        if (t + 2 < T) {
            const int k = (t + 2) * 32;
            const int nb = (t + 2) % 3;
            load16(&sA[nb][so], gA + k);
            load16(&sA[nb][so + 2048], gA + rs64 + k);
            load16(&sB[nb][so], gB + k);
            load16(&sB[nb][so + 2048], gB + rs64 + k);
        }
        __builtin_amdgcn_sched_barrier(0);
        __builtin_amdgcn_s_setprio(1);
        #pragma unroll
        for (int mt = 0; mt < 4; mt++)
            #pragma unroll
            for (int nt = 0; nt < 4; nt++)
                acc[mt][nt] = MFMA16(afc[mt], bfc[nt], acc[mt][nt]);
        __builtin_amdgcn_s_setprio(0);
        __builtin_amdgcn_sched_barrier(0);
        if (t + 1 < T) {
            if (t + 2 < T) {
                asm volatile("s_waitcnt vmcnt(4) lgkmcnt(0)" ::: "memory");
            } else {
                asm volatile("s_waitcnt vmcnt(0) lgkmcnt(0)" ::: "memory");
            }
            asm volatile("s_barrier" ::: "memory");
            const int nb = (t + 1) % 3;
            afn[0] = *(const bf16x8*)&sA[nb][(wm + ln) * 32 + swr];
            #pragma unroll
            for (int nt = 0; nt < 4; nt++)
                bfn[nt] = *(const bf16x8*)&sB[nb][(wn + nt * 16 + ln) * 32 + swr];
            #pragma unroll
            for (int mt = 1; mt < 4; mt++)
                afn[mt] = *(const bf16x8*)&sA[nb][(wm + mt * 16 + ln) * 32 + swr];
        }
    };

    #pragma unroll 1
    for (int t = 0; t < T; t += 2) {
        step(t, fa0, fb0, fa1, fb1);
        step(t + 1, fa1, fb1, fa0, fb0);
    }

    const size_t rowb = m0 + wm + quad * 4;
    const int colb = n0 + wn + ln;
    #pragma unroll
    for (int mt = 0; mt < 4; mt++) {
        #pragma unroll
        for (int nt = 0; nt < 4; nt++) {
            const int n = colb + nt * 16;
            const float bs = bias[n];
            #pragma unroll
            for (int r = 0; r < 4; r++) {
                const size_t row = rowb + mt * 16 + r;
                float c = acc[mt][nt][r] + bs;
                if constexpr (EPI == 0) {
                    int sect = n >> 10, d1 = n & 1023, h = d1 >> 6, d = d1 & 63;
                    int bb = (int)(row >> 11), s = (int)(row & 2047);
                    size_t bh = (size_t)(bb * 16 + h);
                    if (sect == 0)      ob0[(bh * 2048 + s) * 64 + d] = f2b(c);
                    else if (sect == 1) ob1[(bh * 2048 + s) * 64 + d] = f2b(c);
                    else                ob2[(bh * 64 + d) * 2048 + s] = f2b(c);  // V^T
                } else if constexpr (EPI == 1) {
                    size_t idx = row * 1024 + n;
                    ob0[idx] = f2b(c);                 // ctx (pre-residual) for INL
                    of0[idx] = xres[idx] + c;          // x1 = x + attn_out
                } else if constexpr (EPI == 2) {
                    int p = n >> 10;
                    float v;
                    if (p == 0)       v = c;                                            // u
                    else if (p == 2)  v = fmaxf(c, 0.f) + log1pf(__expf(-fabsf(c)));    // softplus
                    else              v = 1.f / (1.f + __expf(-c));                     // sigmoid
                    ob0[row * 4096 + n] = f2b(v);
                } else {
                    float v = 0.5f * c * (1.f + erff(c * 0.70710678118654752f));        // exact GELU
                    ob0[row * 4096 + n] = f2b(v);
                }
            }
        }
    }
}

// ---------------------------------------------------------------------------
// gemm64: 128x128 tile, BK=64, 2-buf LDS, both-sides granule swizzle (R9
// config — winner at K=4096).  Used for EPI4 (FF2) only.
// ---------------------------------------------------------------------------
__global__ __launch_bounds__(256, 2) void gemm64_ff2(const unsigned short* __restrict__ A,
                                                     const unsigned short* __restrict__ W,
                                                     const float* __restrict__ bias, int K,
                                                     float* __restrict__ of0) {
    __shared__ unsigned short sA[2][128 * 64];
    __shared__ unsigned short sB[2][128 * 64];
    const int tid = threadIdx.x;
    const int wave = tid >> 6, lane = tid & 63;
    const int ln = lane & 15, quad = lane >> 4;
    const size_t m0 = (size_t)blockIdx.y * 128;
    const int n0 = blockIdx.x * 128;
    const int wm = (wave >> 1) * 64, wn = (wave & 1) * 64;

    const floatx4 z4 = {0.f, 0.f, 0.f, 0.f};
    floatx4 acc[4][4];
    #pragma unroll
    for (int mt = 0; mt < 4; mt++)
        #pragma unroll
        for (int nt = 0; nt < 4; nt++) acc[mt][nt] = z4;

    const int srow = tid >> 3;                        // 0..31
    const int ssw  = ((tid & 7) ^ (srow & 7)) * 8;    // source col (ushorts)
    const unsigned short* gA = A + (m0 + srow) * K + ssw;
    const unsigned short* gB = W + ((size_t)(n0 + srow)) * K + ssw;
    const size_t rs32 = (size_t)32 * K;
    const int lwb = wave * 512;

    auto stage = [&](int buf, int t) {
        const unsigned short* a = gA + (size_t)t * 64;
        const unsigned short* b = gB + (size_t)t * 64;
        #pragma unroll
        for (int j = 0; j < 4; j++) {
            load16(&sA[buf][j * 2048 + lwb], a + j * rs32);
            load16(&sB[buf][j * 2048 + lwb], b + j * rs32);
        }
    };

    const int lnx = ln & 7;
    const int ga0 = (quad ^ lnx) * 8;
    const int ga1 = ((quad + 4) ^ lnx) * 8;
    bf16x8 fa[4], fb[4];
    auto ldfrag = [&](int buf, int ga) {
        #pragma unroll
        for (int mt = 0; mt < 4; mt++)
            fa[mt] = *(const bf16x8*)&sA[buf][(wm + mt * 16 + ln) * 64 + ga];
        #pragma unroll
        for (int nt = 0; nt < 4; nt++)
            fb[nt] = *(const bf16x8*)&sB[buf][(wn + nt * 16 + ln) * 64 + ga];
    };
    auto mmah = [&]() {
        __builtin_amdgcn_s_setprio(1);
        #pragma unroll
        for (int mt = 0; mt < 4; mt++)
            #pragma unroll
            for (int nt = 0; nt < 4; nt++)
                acc[mt][nt] = MFMA16(fa[mt], fb[nt], acc[mt][nt]);
        __builtin_amdgcn_s_setprio(0);
    };

    const int T = K >> 6;

    stage(0, 0);
    asm volatile("s_waitcnt vmcnt(0)" ::: "memory");
    asm volatile("s_barrier" ::: "memory");

    #pragma unroll 1
    for (int t = 0; t < T; t++) {
        const int c = t & 1;
        if (t + 1 < T) stage(c ^ 1, t + 1);
        __builtin_amdgcn_sched_barrier(0);
        ldfrag(c, ga0);
        asm volatile("s_waitcnt lgkmcnt(0)" ::: "memory");
        __builtin_amdgcn_sched_barrier(0);
        mmah();
        ldfrag(c, ga1);
        asm volatile("s_waitcnt lgkmcnt(0)" ::: "memory");
        __builtin_amdgcn_sched_barrier(0);
        mmah();
        __builtin_amdgcn_sched_barrier(0);
        if (t + 1 < T) {
            asm volatile("s_waitcnt vmcnt(0)" ::: "memory");
            asm volatile("s_barrier" ::: "memory");
        }
    }

    const size_t rowb = m0 + wm + quad * 4;
    const int colb = n0 + wn + ln;
    #pragma unroll
    for (int mt = 0; mt < 4; mt++) {
        #pragma unroll
        for (int nt = 0; nt < 4; nt++) {
            const int n = colb + nt * 16;
            const float bs = bias[n];
            #pragma unroll
            for (int r = 0; r < 4; r++) {
                const size_t row = rowb + mt * 16 + r;
                of0[row * 1024 + n] += acc[mt][nt][r] + bs;   // final residual accumulate
            }
        }
    }
}

// ---------------------------------------------------------------------------
// Flash causal attention (+ setprio around MFMA clusters).
// ---------------------------------------------------------------------------
#define PSTR 72
__global__ __launch_bounds__(256, 3) void attn_kernel(const unsigned short* __restrict__ Qb,
                                                      const unsigned short* __restrict__ Kb,
                                                      const unsigned short* __restrict__ Vtb,
                                                      unsigned short* __restrict__ Ob) {
    __shared__ unsigned short sK[2][64 * 64];
    __shared__ unsigned short sVt[2][64 * 64];
    __shared__ unsigned short sQP[128 * PSTR];
    const int pr = blockIdx.x;
    const int bh = blockIdx.y;
    const int tid = threadIdx.x, wave = tid >> 6, lane = tid & 63;
    const int ln = lane & 15, quad = lane >> 4;
    const unsigned short* Q  = Qb  + (size_t)bh * 2048 * 64;
    const unsigned short* Kp = Kb  + (size_t)bh * 2048 * 64;
    const unsigned short* Vt = Vtb + (size_t)bh * 64 * 2048;

    const int rl  = lane >> 3;
    const int gsw = (((lane & 7) ^ rl)) * 8;
    const int sseg = wave * 2;
    const unsigned short* kbase = Kp + (size_t)(sseg * 8 + rl) * 64 + gsw;
    const unsigned short* vbase = Vt + (size_t)(sseg * 8 + rl) * 2048 + gsw;
    unsigned short* sP = &sQP[wave * 32 * PSTR];
    const int bb = bh >> 4, h = bh & 15;
    const floatx4 z4 = {0.f, 0.f, 0.f, 0.f};

    #pragma unroll 1
    for (int phase = 0; phase < 2; phase++) {
        const int qt = phase ? pr : (15 - pr);
        const int q0 = qt * 128;
        const int T = 2 * qt + 2;

        #pragma unroll
        for (int i = 0; i < 4; i++) {
            int s = wave * 4 + i;
            load16(&sQP[s * 512], Q + (size_t)(q0 + s * 8 + rl) * 64 + gsw);
        }
        load16(&sK[0][sseg * 512], kbase);
        load16(&sK[0][(sseg + 1) * 512], kbase + (size_t)8 * 64);
        load16(&sVt[0][sseg * 512], vbase);
        load16(&sVt[0][(sseg + 1) * 512], vbase + (size_t)8 * 2048);
        asm volatile("s_waitcnt vmcnt(0)" ::: "memory");
        asm volatile("s_barrier" ::: "memory");

        bf16x8 aq[2][2];
        #pragma unroll
        for (int mt = 0; mt < 2; mt++)
            #pragma unroll
            for (int ks = 0; ks < 2; ks++)
                aq[mt][ks] = *(const bf16x8*)&sQP[(wave * 32 + mt * 16 + ln) * 64 +
                                                  (((ks * 4 + quad) ^ (ln & 7)) * 8)];
        asm volatile("s_waitcnt lgkmcnt(0)" ::: "memory");
        asm volatile("s_barrier" ::: "memory");

        floatx4 Oacc[2][4];
        float m_run[2][4], l_run[2][4];
        #pragma unroll
        for (int mt = 0; mt < 2; mt++)
            #pragma unroll
            for (int j = 0; j < 4; j++) { Oacc[mt][j] = z4; m_run[mt][j] = -1e30f; l_run[mt][j] = 0.f; }

        const int wave_first = q0 + wave * 32;
        const int wave_last  = wave_first + 31;

        #pragma unroll 1
        for (int t = 0; t < T; t++) {
            const int kk0 = t * 64;
            const int cur = t & 1;
            if (t + 1 < T) {
                const unsigned short* kg = kbase + (size_t)(kk0 + 64) * 64;
                const unsigned short* vg = vbase + (size_t)(kk0 + 64);
                load16(&sK[cur ^ 1][sseg * 512], kg);
                load16(&sK[cur ^ 1][(sseg + 1) * 512], kg + (size_t)8 * 64);
                load16(&sVt[cur ^ 1][sseg * 512], vg);
                load16(&sVt[cur ^ 1][(sseg + 1) * 512], vg + (size_t)8 * 2048);
                asm volatile("s_waitcnt vmcnt(4)" ::: "memory");
            } else {
                asm volatile("s_waitcnt vmcnt(0)" ::: "memory");
            }
            asm volatile("s_barrier" ::: "memory");

            if (kk0 <= wave_last) {
                floatx4 Sc[2][4];
                #pragma unroll
                for (int mt = 0; mt < 2; mt++)
                    #pragma unroll
                    for (int nt = 0; nt < 4; nt++) Sc[mt][nt] = z4;
                __builtin_amdgcn_s_setprio(1);
                #pragma unroll
                for (int ks = 0; ks < 2; ks++) {
                    #pragma unroll
                    for (int nt = 0; nt < 4; nt++) {
                        bf16x8 bk = *(const bf16x8*)&sK[cur][(nt * 16 + ln) * 64 +
                                                             (((ks * 4 + quad) ^ (ln & 7)) * 8)];
                        #pragma unroll
                        for (int mt = 0; mt < 2; mt++)
                            Sc[mt][nt] = MFMA16(aq[mt][ks], bk, Sc[mt][nt]);
                    }
                }
                __builtin_amdgcn_s_setprio(0);
                const bool diag = (kk0 + 63 > wave_first);
                #pragma unroll
                for (int mt = 0; mt < 2; mt++)
                    #pragma unroll
                    for (int nt = 0; nt < 4; nt++)
                        #pragma unroll
                        for (int r = 0; r < 4; r++) {
                            float v = Sc[mt][nt][r] * 0.125f;
                            if (diag) {
                                int rowg = wave_first + mt * 16 + quad * 4 + r;
                                int colg = kk0 + nt * 16 + ln;
                                if (colg > rowg) v = -1e30f;
                            }
                            Sc[mt][nt][r] = v;
                        }
                float alpha[2][4];
                #pragma unroll
                for (int mt = 0; mt < 2; mt++)
                    #pragma unroll
                    for (int r = 0; r < 4; r++) {
                        float mx = fmaxf(fmaxf(Sc[mt][0][r], Sc[mt][1][r]), fmaxf(Sc[mt][2][r], Sc[mt][3][r]));
                        #pragma unroll
                        for (int off = 1; off < 16; off <<= 1) mx = fmaxf(mx, __shfl_xor(mx, off));
                        float mnew = fmaxf(m_run[mt][r], mx);
                        alpha[mt][r] = __expf(m_run[mt][r] - mnew);
                        m_run[mt][r] = mnew;
                    }
                #pragma unroll
                for (int mt = 0; mt < 2; mt++)
                    #pragma unroll
                    for (int r = 0; r < 4; r++) {
                        float rs = 0.f;
                        #pragma unroll
                        for (int nt = 0; nt < 4; nt++) {
                            float p = __expf(Sc[mt][nt][r] - m_run[mt][r]);
                            Sc[mt][nt][r] = p;
                            rs += p;
                        }
                        #pragma unroll
                        for (int off = 1; off < 16; off <<= 1) rs += __shfl_xor(rs, off);
                        l_run[mt][r] = l_run[mt][r] * alpha[mt][r] + rs;
                    }
                #pragma unroll
                for (int mt = 0; mt < 2; mt++)
                    #pragma unroll
                    for (int nt = 0; nt < 4; nt++)
                        #pragma unroll
                        for (int r = 0; r < 4; r++) Oacc[mt][nt][r] *= alpha[mt][r];
                #pragma unroll
                for (int mt = 0; mt < 2; mt++)
                    #pragma unroll
                    for (int nt = 0; nt < 4; nt++)
                        #pragma unroll
                        for (int r = 0; r < 4; r++)
                            sP[(mt * 16 + quad * 4 + r) * PSTR + nt * 16 + ln] = f2b(Sc[mt][nt][r]);
                __builtin_amdgcn_s_setprio(1);
                #pragma unroll
                for (int kp = 0; kp < 2; kp++) {
                    bf16x8 ap[2];
                    #pragma unroll
                    for (int mt = 0; mt < 2; mt++)
                        ap[mt] = *(const bf16x8*)&sP[(mt * 16 + ln) * PSTR + kp * 32 + quad * 8];
                    #pragma unroll
                    for (int nt = 0; nt < 4; nt++) {
                        bf16x8 bv = *(const bf16x8*)&sVt[cur][(nt * 16 + ln) * 64 +
                                                              (((kp * 4 + quad) ^ (ln & 7)) * 8)];
                        #pragma unroll
                        for (int mt = 0; mt < 2; mt++)
                            Oacc[mt][nt] = MFMA16(ap[mt], bv, Oacc[mt][nt]);
                    }
                }
                __builtin_amdgcn_s_setprio(0);
            }
            asm volatile("s_barrier" ::: "memory");
        }

        #pragma unroll
        for (int mt = 0; mt < 2; mt++)
            #pragma unroll
            for (int nt = 0; nt < 4; nt++)
                #pragma unroll
                for (int r = 0; r < 4; r++) {
                    float o = Oacc[mt][nt][r] / l_run[mt][r];
                    int srow = q0 + wave * 32 + mt * 16 + quad * 4 + r;
                    size_t tok = (size_t)bb * 2048 + srow;
                    Ob[tok * 1024 + h * 64 + nt * 16 + ln] = f2b(o);
                }
    }
}

// ---------------------------------------------------------------------------
extern "C" void kernel_launch(void* const* d_in, const int* in_sizes, int n_in,
                              void* d_out, int out_size, void* d_ws, size_t ws_size,
                              hipStream_t stream) {
    const float* x          = (const float*)d_in[0];
    const float* ln_attn_w  = (const float*)d_in[1];
    const float* ln_attn_b  = (const float*)d_in[2];
    const float* attn_in_w  = (const float*)d_in[3];
    const float* attn_in_b  = (const float*)d_in[4];
    const float* attn_out_w = (const float*)d_in[5];
    const float* attn_out_b = (const float*)d_in[6];
    const float* ln1_w      = (const float*)d_in[7];
    const float* ln1_b      = (const float*)d_in[8];
    const float* ln2_w      = (const float*)d_in[9];
    const float* ln2_b      = (const float*)d_in[10];
    const float* inl_u_w    = (const float*)d_in[11];
    const float* inl_u_b    = (const float*)d_in[12];
    const float* inl_a_w    = (const float*)d_in[13];
    const float* inl_a_b    = (const float*)d_in[14];
    const float* inl_b_w    = (const float*)d_in[15];
    const float* inl_b_b    = (const float*)d_in[16];
    const float* inl_g_w    = (const float*)d_in[17];
    const float* inl_g_b    = (const float*)d_in[18];
    const float* ff1_w      = (const float*)d_in[19];
    const float* ff1_b      = (const float*)d_in[20];
    const float* ff2_w      = (const float*)d_in[21];
    const float* ff2_b      = (const float*)d_in[22];
    float* out = (float*)d_out;

    char* ws = (char*)d_ws;
    unsigned short* Wqkv  = (unsigned short*)(ws);
    unsigned short* Wout  = (unsigned short*)(ws + 6291456);
    unsigned short* Winl  = (unsigned short*)(ws + 8388608);
    unsigned short* Wff1  = (unsigned short*)(ws + 16777216);
    unsigned short* Wff2  = (unsigned short*)(ws + 25165824);
    unsigned short* xnb   = (unsigned short*)(ws + 33554432);   // 16MB: xn, later h
    unsigned short* qb    = (unsigned short*)(ws + 50331648);   // 16MB
    unsigned short* kb    = (unsigned short*)(ws + 67108864);   // 16MB
    unsigned short* vtb   = (unsigned short*)(ws + 83886080);   // 16MB
    unsigned short* attnb = (unsigned short*)(ws + 100663296);  // 16MB
    unsigned short* ctxb  = (unsigned short*)(ws + 117440512);  // 16MB
    float*          bias4 = (float*)(ws + 167772160);           // 16KB
    unsigned short* uabg  = (unsigned short*)(ws + 50331648);   // 64MB, reuses q/k/vt/attn
    unsigned short* ff1b  = (unsigned short*)(ws + 50331648);   // 64MB, reuses uabg

    // 1. fused weight conversion (one launch) + bias concat
    cvt_all<<<16384, 256, 0, stream>>>(attn_in_w, attn_out_w, inl_u_w, inl_a_w,
                                       inl_b_w, inl_g_w, ff1_w, ff2_w,
                                       Wqkv, Wout, Winl, Winl + 1048576,
                                       Winl + 2097152, Winl + 3145728, Wff1, Wff2);
    catbias_kernel<<<16, 256, 0, stream>>>(inl_u_b, inl_a_b, inl_b_b, inl_g_b, bias4);

    // 2. xn = LN(x)
    ln_kernel<<<8192, 256, 0, stream>>>(x, ln_attn_w, ln_attn_b, xnb);
    // 3. qkv projection, scattered into per-head q/k/v^T  (BK=32 variant)
    gemm32<0><<<dim3(24, 64), 256, 0, stream>>>(xnb, Wqkv, attn_in_b, 1024, qb, kb, vtb, nullptr, nullptr);
    // 4. causal flash attention (balanced pairs)
    attn_kernel<<<dim3(8, 64), 256, 0, stream>>>(qb, kb, vtb, attnb);
    // 5. out-projection: ctx (bf16) + x1 = x + ctx -> d_out  (BK=32)
    gemm32<1><<<dim3(8, 64), 256, 0, stream>>>(attnb, Wout, attn_out_b, 1024, ctxb, nullptr, nullptr, out, x);
    // 6. fused INL controllers  (BK=32)
    gemm32<2><<<dim3(32, 64), 256, 0, stream>>>(ctxb, Winl, bias4, 1024, uabg, nullptr, nullptr, nullptr, nullptr);
    // 7. FUSED ln1 + integrator + ln2: x2 -> d_out, h -> xnb
    integrator_ln_kernel<<<8192, 256, 0, stream>>>(ln1_w, ln1_b, ln2_w, ln2_b, uabg, out, xnb);
    // 8. FF1 + exact GELU  (BK=32)
    gemm32<3><<<dim3(32, 64), 256, 0, stream>>>(xnb, Wff1, ff1_b, 1024, ff1b, nullptr, nullptr, nullptr, nullptr);
    // 9. FF2 + residual accumulate -> d_out  (BK=64 variant — winner at K=4096)
    gemm64_ff2<<<dim3(8, 64), 256, 0, stream>>>(ff1b, Wff2, ff2_b, 4096, out);
}